// Round 14
// baseline (149.353 us; speedup 1.0000x reference)
//
#include <hip/hip_runtime.h>

#define DIM 1024
#define HEADS 16
#define HD 64
#define BATCH 2
#define SEQ 2048
#define ROWS (BATCH*SEQ)          // 4096
#define EPS 1e-6f

typedef float f32x4  __attribute__((ext_vector_type(4)));
typedef float f32x16 __attribute__((ext_vector_type(16)));
typedef short s16x4  __attribute__((ext_vector_type(4)));
typedef short s16x8  __attribute__((ext_vector_type(8)));

static __device__ __forceinline__ short f2bf(float f) {
    union { float f; unsigned u; } x; x.f = f;
    unsigned r = x.u + 0x7FFFu + ((x.u >> 16) & 1u);
    return (short)(r >> 16);
}
static __device__ __forceinline__ s16x8 pack8(float4 lo, float4 hi) {
    s16x8 r;
    r[0]=f2bf(lo.x); r[1]=f2bf(lo.y); r[2]=f2bf(lo.z); r[3]=f2bf(lo.w);
    r[4]=f2bf(hi.x); r[5]=f2bf(hi.y); r[6]=f2bf(hi.z); r[7]=f2bf(hi.w);
    return r;
}
static __device__ __forceinline__ unsigned cvtpk(float a, float b) {
    unsigned r;
    asm("v_cvt_pk_bf16_f32 %0, %1, %2" : "=v"(r) : "v"(a), "v"(b));
    return r;
}
static __device__ __forceinline__ void gld16(short* l, const short* g) {
    __builtin_amdgcn_global_load_lds(
        (const __attribute__((address_space(1))) void*)g,
        (__attribute__((address_space(3))) void*)l, 16, 0, 0);
}

#define MFMA32(A,B,C) __builtin_amdgcn_mfma_f32_32x32x16_bf16(A, B, C, 0, 0, 0)
#define MFMA16(A,B,C) __builtin_amdgcn_mfma_f32_16x16x32_bf16(A, B, C, 0, 0, 0)

struct PA { s16x8 a, b; };
// P (lane's 32 keys for its q-col) -> two bf16 A-fragments (T12; proven r2-r13)
static __device__ __forceinline__ PA packP(const f32x16& s) {
    PA r;
    unsigned A0 = cvtpk(s[0], s[1]),  A1 = cvtpk(s[2], s[3]);
    unsigned B0 = cvtpk(s[4], s[5]),  B1 = cvtpk(s[6], s[7]);
    asm volatile("v_permlane32_swap_b32 %0, %1" : "+v"(A0), "+v"(B0));
    asm volatile("v_permlane32_swap_b32 %0, %1" : "+v"(A1), "+v"(B1));
    union { s16x8 v; unsigned u[4]; } w;
    w.u[0]=A0; w.u[1]=A1; w.u[2]=B0; w.u[3]=B1;
    r.a = w.v;
    unsigned C0 = cvtpk(s[8], s[9]),   C1 = cvtpk(s[10], s[11]);
    unsigned D0 = cvtpk(s[12], s[13]), D1 = cvtpk(s[14], s[15]);
    asm volatile("v_permlane32_swap_b32 %0, %1" : "+v"(C0), "+v"(D0));
    asm volatile("v_permlane32_swap_b32 %0, %1" : "+v"(C1), "+v"(D1));
    union { s16x8 v; unsigned u[4]; } w2;
    w2.u[0]=C0; w2.u[1]=C1; w2.u[2]=D0; w2.u[3]=D1;
    r.b = w2.v;
    return r;
}
static __device__ __forceinline__ float tree_max(const f32x16& s) {
    float t[8];
    #pragma unroll
    for (int i = 0; i < 8; i++) t[i] = fmaxf(s[i], s[i+8]);
    #pragma unroll
    for (int i = 0; i < 4; i++) t[i] = fmaxf(t[i], t[i+4]);
    return fmaxf(fmaxf(t[0], t[2]), fmaxf(t[1], t[3]));
}
static __device__ __forceinline__ float tree_sum(const f32x16& s) {
    float t[8];
    #pragma unroll
    for (int i = 0; i < 8; i++) t[i] = s[i] + s[i+8];
    #pragma unroll
    for (int i = 0; i < 4; i++) t[i] += t[i+4];
    return (t[0] + t[2]) + (t[1] + t[3]);
}

// ---------------------------------------------------------------------------
// fp32 -> bf16 conversion for x, W_qkv, W_proj (one pass, vectorized)
// ---------------------------------------------------------------------------
__global__ __launch_bounds__(256) void convert3(
    const float* __restrict__ x, const float* __restrict__ wq,
    const float* __restrict__ wp,
    short* __restrict__ xb, short* __restrict__ wqb, short* __restrict__ wpb)
{
    const int idx = blockIdx.x * 256 + threadIdx.x;   // one 8-elem chunk
    const int C1 = 4194304/8, C2 = 3145728/8;
    const float* src; short* dst; int off;
    if (idx < C1)            { src = x;  dst = xb;  off = idx; }
    else if (idx < C1 + C2)  { src = wq; dst = wqb; off = idx - C1; }
    else                     { src = wp; dst = wpb; off = idx - C1 - C2; }
    float4 a = ((const float4*)src)[off*2];
    float4 b = ((const float4*)src)[off*2 + 1];
    ((s16x8*)dst)[off] = pack8(a, b);
}

// ---------------------------------------------------------------------------
// bf16 GEMM, m97 structure: 128x128 tile, BK=64, global_load_lds staging.
// MODE 0: fused per-head LayerNorm on q/k; q row-major; K/V written directly
//         in MFMA-fragment order (KP/VP). MODE 1: bias add, fp32 out.
// ---------------------------------------------------------------------------
#define BKG 64

template<int MODE>
__global__ __launch_bounds__(256) void gemm_bf16(
    const short* __restrict__ A, const short* __restrict__ W,
    const float* __restrict__ bias,
    const float* __restrict__ qg, const float* __restrict__ qbeta,
    const float* __restrict__ kg, const float* __restrict__ kbeta,
    short* __restrict__ qb, short* __restrict__ kpb, short* __restrict__ vpb,
    float* __restrict__ out)
{
    alignas(16) __shared__ short As[128*BKG];
    alignas(16) __shared__ short Bs[128*BKG];
    const int tid  = threadIdx.x;
    const int lane = tid & 63, wave = tid >> 6;
    const int wr = wave >> 1, wc = wave & 1;
    const int c = lane & 15, g = lane >> 4;
    const int brow = blockIdx.y * 128, bcol = blockIdx.x * 128;

    const int srow = lane >> 3;
    const int scol = (lane & 7) * 8;
    const short* ag = A + (size_t)(brow + srow)*DIM + scol;
    const short* wg = W + (size_t)(bcol + srow)*DIM + scol;

    f32x4 acc[4][4] = {};

    for (int k0 = 0; k0 < DIM; k0 += BKG) {
        #pragma unroll
        for (int j = 0; j < 4; j++) {
            const int rg = (wave*4 + j) * 8;
            gld16(&As[rg*BKG], ag + (size_t)rg*DIM + k0);
            gld16(&Bs[rg*BKG], wg + (size_t)rg*DIM + k0);
        }
        __syncthreads();

        #pragma unroll
        for (int ks = 0; ks < 2; ks++) {
            s16x8 af[4], bf[4];
            #pragma unroll
            for (int m = 0; m < 4; m++)
                af[m] = *(const s16x8*)&As[(wr*64 + m*16 + c)*BKG + ks*32 + g*8];
            #pragma unroll
            for (int n = 0; n < 4; n++)
                bf[n] = *(const s16x8*)&Bs[(wc*64 + n*16 + c)*BKG + ks*32 + g*8];
            #pragma unroll
            for (int m = 0; m < 4; m++)
                #pragma unroll
                for (int n = 0; n < 4; n++)
                    acc[m][n] = MFMA16(af[m], bf[n], acc[m][n]);
        }
        __syncthreads();
    }

    if (MODE == 0) {
        const int colbase = bcol + wc*64;
        const int t = colbase >> 10;               // 0:q 1:k 2:v
        const int h = (colbase >> 6) & 15;
        float gam[4], bet[4];
        float scale = 1.0f;
        if (t < 2) {
            const float* G  = (t == 0) ? qg : kg;
            const float* Bt = (t == 0) ? qbeta : kbeta;
            #pragma unroll
            for (int n = 0; n < 4; n++) { gam[n] = G[n*16 + c]; bet[n] = Bt[n*16 + c]; }
            if (t == 0) scale = 0.125f * 1.44269504088896340736f;  // D^-0.5 * log2e
        }
        #pragma unroll
        for (int m = 0; m < 4; m++) {
            #pragma unroll
            for (int j = 0; j < 4; j++) {
                const int row = brow + wr*64 + m*16 + g*4 + j;
                const int bi = row >> 11, ni = row & (SEQ-1);
                const int bh = bi*HEADS + h;
                float v0 = acc[m][0][j], v1 = acc[m][1][j];
                float v2 = acc[m][2][j], v3 = acc[m][3][j];
                if (t < 2) {
                    float s = (v0 + v1) + (v2 + v3);
                    s += __shfl_xor(s, 1); s += __shfl_xor(s, 2);
                    s += __shfl_xor(s, 4); s += __shfl_xor(s, 8);
                    const float mu = s * 0.015625f;
                    v0 -= mu; v1 -= mu; v2 -= mu; v3 -= mu;
                    float vv = (v0*v0 + v1*v1) + (v2*v2 + v3*v3);
                    vv += __shfl_xor(vv, 1); vv += __shfl_xor(vv, 2);
                    vv += __shfl_xor(vv, 4); vv += __shfl_xor(vv, 8);
                    const float rstd = rsqrtf(vv * 0.015625f + EPS);
                    v0 = (v0*rstd*gam[0] + bet[0]) * scale;
                    v1 = (v1*rstd*gam[1] + bet[1]) * scale;
                    v2 = (v2*rstd*gam[2] + bet[2]) * scale;
                    v3 = (v3*rstd*gam[3] + bet[3]) * scale;
                }
                if (t == 0) {
                    const size_t rb = ((size_t)bh*SEQ + ni)*HD;
                    qb[rb + 0*16 + c] = f2bf(v0);
                    qb[rb + 1*16 + c] = f2bf(v1);
                    qb[rb + 2*16 + c] = f2bf(v2);
                    qb[rb + 3*16 + c] = f2bf(v3);
                } else {
                    const size_t tb = ((size_t)bh*64 + (ni >> 5)) * 2048;
                    const int kl = ni & 31;
                    if (t == 1) {
                        const size_t b2 = tb + (size_t)(((c >> 3)*32 + kl)*8 + (c & 7));
                        kpb[b2 + 0*512] = f2bf(v0);
                        kpb[b2 + 1*512] = f2bf(v1);
                        kpb[b2 + 2*512] = f2bf(v2);
                        kpb[b2 + 3*512] = f2bf(v3);
                    } else {
                        const int hi2 = (kl & 15) >> 3, e2 = kl & 7;
                        const size_t b0 = tb + (size_t)((2*(kl >> 4))*512 + (hi2*32)*8 + e2);
                        vpb[b0 + (size_t)(c)*8]        = f2bf(v0);
                        vpb[b0 + (size_t)(16 + c)*8]   = f2bf(v1);
                        vpb[b0 + 512 + (size_t)(c)*8]      = f2bf(v2);
                        vpb[b0 + 512 + (size_t)(16 + c)*8] = f2bf(v3);
                    }
                }
            }
        }
    } else {
        #pragma unroll
        for (int n = 0; n < 4; n++) {
            const int col = bcol + wc*64 + n*16 + c;
            const float bv = bias[col];
            #pragma unroll
            for (int m = 0; m < 4; m++) {
                #pragma unroll
                for (int j = 0; j < 4; j++) {
                    const int row = brow + wr*64 + m*16 + g*4 + j;
                    out[(size_t)row*DIM + col] = acc[m][n][j] + bv;
                }
            }
        }
    }
}

// ---------------------------------------------------------------------------
// Flash attention: r13 structure (q32/wave, 2-way split-K, launch_bounds
// (256,4), shfl_xor max reduce, exp2f, T12/T13, 2-way LDS merge) +
// (1) deferred cross-half sum: l accumulates per half-lane, single
//     shfl_xor(l,32) after the loop (exact: rescale factors identical in
//     mirror lanes since m syncs via the max shuffle);
// (2) depth-2 kc pipeline: kcA/kcB banks, 2x-unrolled loop, each K-tile
//     load has ~2 iters (~1200 cyc) of cover before its MFMA use.
// ---------------------------------------------------------------------------
#define ATTN_STEP(KBANK, t)                                                   \
    {                                                                         \
        /* S^T = K(tile t) * Q */                                             \
        f32x16 s = {};                                                        \
        __builtin_amdgcn_s_setprio(1);                                        \
        s = MFMA32(KBANK##0, qf[0], s);                                       \
        s = MFMA32(KBANK##1, qf[1], s);                                       \
        s = MFMA32(KBANK##2, qf[2], s);                                       \
        s = MFMA32(KBANK##3, qf[3], s);                                       \
        __builtin_amdgcn_s_setprio(0);                                        \
        /* refill this bank with tile (t)+2 (cover: 2 full iters) */          \
        {                                                                     \
            const int nk_ = (((t) + 2) & 31) * 2048;                          \
            KBANK##0 = *(const s16x8*)(kp + nk_);                             \
            KBANK##1 = *(const s16x8*)(kp + nk_ + 512);                       \
            KBANK##2 = *(const s16x8*)(kp + nk_ + 1024);                      \
            KBANK##3 = *(const s16x8*)(kp + nk_ + 1536);                      \
        }                                                                     \
        __builtin_amdgcn_sched_barrier(0);                                    \
        /* softmax: max shuffle kept (m must be row-common); sum deferred */  \
        float pmax_ = tree_max(s);                                            \
        pmax_ = fmaxf(pmax_, __shfl_xor(pmax_, 32));                          \
        if (!__all(pmax_ - m <= 8.0f)) {          /* T13 */                   \
            float mn_ = fmaxf(m, pmax_);                                      \
            float corr_ = exp2f(m - mn_);                                     \
            _Pragma("unroll")                                                 \
            for (int i_ = 0; i_ < 16; i_++) { o0[i_] *= corr_; o1[i_] *= corr_; } \
            l *= corr_;                                                       \
            m = mn_;                                                          \
        }                                                                     \
        _Pragma("unroll")                                                     \
        for (int i_ = 0; i_ < 16; i_++) s[i_] = exp2f(s[i_] - m);             \
        l += tree_sum(s);                         /* per half-lane partial */ \
        PA pa_ = packP(s);                                                    \
        /* O^T += V^T(tile t) * P */                                          \
        __builtin_amdgcn_s_setprio(1);                                        \
        o0 = MFMA32(vc0, pa_.a, o0);                                          \
        o1 = MFMA32(vc1, pa_.a, o1);                                          \
        o0 = MFMA32(vc2, pa_.b, o0);                                          \
        o1 = MFMA32(vc3, pa_.b, o1);                                          \
        __builtin_amdgcn_s_setprio(0);                                        \
        /* refill vc with tile (t)+1 (cover: ~1 iter) */                      \
        {                                                                     \
            const int nv_ = (((t) + 1) & 31) * 2048;                          \
            vc0 = *(const s16x8*)(vp + nv_);                                  \
            vc1 = *(const s16x8*)(vp + nv_ + 512);                            \
            vc2 = *(const s16x8*)(vp + nv_ + 1024);                           \
            vc3 = *(const s16x8*)(vp + nv_ + 1536);                           \
        }                                                                     \
    }

__global__ __launch_bounds__(256, 4) void attn_kernel(
    const short* __restrict__ qbuf, const short* __restrict__ KP,
    const short* __restrict__ VP, short* __restrict__ aout)
{
    alignas(16) __shared__ float OL[2][64][32];   // [qsub][lane][reg]
    __shared__ float ML[2][2][64];                // [qsub][{m,l}][lane]

    const int bh = blockIdx.x, qt = blockIdx.y;
    const int tid = threadIdx.x, wave = tid >> 6, lane = tid & 63;
    const int qsub = wave >> 1, half = wave & 1;
    const int l31 = lane & 31, hi = lane >> 5;
    const int q0 = qt*64 + qsub*32;

    s16x8 qf[4];
    const short* qrow = qbuf + ((size_t)bh*SEQ + q0 + l31)*HD + 8*hi;
    #pragma unroll
    for (int ks = 0; ks < 4; ks++) qf[ks] = *(const s16x8*)(qrow + 16*ks);

    const short* kp = KP + ((size_t)bh*64 + half*32)*2048 + lane*8;
    const short* vp = VP + ((size_t)bh*64 + half*32)*2048 + lane*8;

    // prologue: kcA <- tile0, kcB <- tile1, vc <- tile0
    s16x8 kA0 = *(const s16x8*)(kp);
    s16x8 kA1 = *(const s16x8*)(kp + 512);
    s16x8 kA2 = *(const s16x8*)(kp + 1024);
    s16x8 kA3 = *(const s16x8*)(kp + 1536);
    s16x8 kB0 = *(const s16x8*)(kp + 2048);
    s16x8 kB1 = *(const s16x8*)(kp + 2048 + 512);
    s16x8 kB2 = *(const s16x8*)(kp + 2048 + 1024);
    s16x8 kB3 = *(const s16x8*)(kp + 2048 + 1536);
    s16x8 vc0 = *(const s16x8*)(vp);
    s16x8 vc1 = *(const s16x8*)(vp + 512);
    s16x8 vc2 = *(const s16x8*)(vp + 1024);
    s16x8 vc3 = *(const s16x8*)(vp + 1536);

    f32x16 o0 = {}, o1 = {};
    float m = -1e30f, l = 0.f;

    #pragma unroll 1
    for (int it = 0; it < 32; it += 2) {
        ATTN_STEP(kA, it)       // tile it   (kA refilled with it+2)
        ATTN_STEP(kB, it + 1)   // tile it+1 (kB refilled with it+3)
    }

    // deferred cross-half sum (exact; m was row-common throughout)
    l += __shfl_xor(l, 32);

    // ---- merge the two K-halves (r13 exact) ----
    if (half == 1) {
        float* ob = &OL[qsub][lane][0];
        #pragma unroll
        for (int i = 0; i < 8; i++) {
            const int slot = (i + (lane & 7)) & 7;
            f32x4 v;
            if (i < 4) { v[0]=o0[4*i]; v[1]=o0[4*i+1]; v[2]=o0[4*i+2]; v[3]=o0[4*i+3]; }
            else { const int j = i-4; v[0]=o1[4*j]; v[1]=o1[4*j+1]; v[2]=o1[4*j+2]; v[3]=o1[4*j+3]; }
            *(f32x4*)(ob + slot*4) = v;
        }
        ML[qsub][0][lane] = m;
        ML[qsub][1][lane] = l;
    }
    __syncthreads();
    if (half == 0) {
        const float m1 = ML[qsub][0][lane];
        const float l1 = ML[qsub][1][lane];
        const float ms = fmaxf(m, m1);
        const float c0 = exp2f(m - ms), c1 = exp2f(m1 - ms);
        const float inv = 1.0f / (l*c0 + l1*c1);
        const float* ob = &OL[qsub][lane][0];
        const int b = bh >> 4, h = bh & 15;
        short* dst = aout + ((size_t)(b*SEQ + q0 + l31))*DIM + h*HD;
        #pragma unroll
        for (int i = 0; i < 8; i++) {
            const int slot = (i + (lane & 7)) & 7;
            f32x4 p = *(const f32x4*)(ob + slot*4);
            s16x4 st;
            if (i < 4) {
                #pragma unroll
                for (int j = 0; j < 4; j++) st[j] = f2bf((o0[4*i+j]*c0 + p[j]*c1) * inv);
                *(s16x4*)(dst + 8*i + 4*hi) = st;
            } else {
                const int t3 = i - 4;
                #pragma unroll
                for (int j = 0; j < 4; j++) st[j] = f2bf((o1[4*t3+j]*c0 + p[j]*c1) * inv);
                *(s16x4*)(dst + 32 + 8*t3 + 4*hi) = st;
            }
        }
    }
}

// ---------------------------------------------------------------------------
extern "C" void kernel_launch(void* const* d_in, const int* in_sizes, int n_in,
                              void* d_out, int out_size, void* d_ws, size_t ws_size,
                              hipStream_t stream)
{
    const float* x     = (const float*)d_in[0];
    const float* Wqkv  = (const float*)d_in[1];
    const float* qg    = (const float*)d_in[2];
    const float* qbeta = (const float*)d_in[3];
    const float* kg    = (const float*)d_in[4];
    const float* kbeta = (const float*)d_in[5];
    const float* Wproj = (const float*)d_in[6];
    const float* bproj = (const float*)d_in[7];
    float* out = (float*)d_out;

    char* ws = (char*)d_ws;
    const size_t MB = 1024*1024;
    short* xb     = (short*)(ws);              // 8 MB; dead after gemm<0>
    short* aout   = (short*)(ws);              // reuses xb slot (written by attn)
    short* wqkvb  = (short*)(ws + 8*MB);       // 6 MB
    short* wprojb = (short*)(ws + 14*MB);      // 2 MB (live until gemm<1>)
    short* q      = (short*)(ws + 16*MB);      // 8 MB
    short* KP     = (short*)(ws + 24*MB);      // 8 MB (fragment-order K)
    short* VP     = (short*)(ws + 32*MB);      // 8 MB (fragment-order V)

    // 1. fp32 -> bf16 conversions
    convert3<<<dim3(4096), 256, 0, stream>>>(x, Wqkv, Wproj, xb, wqkvb, wprojb);

    // 2. QKV GEMM + fused q/k LayerNorm + fused K/V fragment repack
    gemm_bf16<0><<<dim3(3*DIM/128, ROWS/128), 256, 0, stream>>>(
        xb, wqkvb, nullptr, qg, qbeta, kg, kbeta, q, KP, VP, nullptr);

    // 3. Flash attention (q32/wave, 2-way split-K, depth-2 kc pipeline)
    attn_kernel<<<dim3(BATCH*HEADS, SEQ/64), 256, 0, stream>>>(q, KP, VP, aout);

    // 4. Projection GEMM + bias -> fp32 d_out
    gemm_bf16<1><<<dim3(DIM/128, ROWS/128), 256, 0, stream>>>(
        aout, wprojb, bproj, nullptr, nullptr, nullptr, nullptr,
        nullptr, nullptr, nullptr, out);
}

// Round 15
// 138.685 us; speedup vs baseline: 1.0769x; 1.0769x over previous
//
#include <hip/hip_runtime.h>

#define DIM 1024
#define HEADS 16
#define HD 64
#define BATCH 2
#define SEQ 2048
#define ROWS (BATCH*SEQ)          // 4096
#define EPS 1e-6f

typedef float f32x4  __attribute__((ext_vector_type(4)));
typedef float f32x16 __attribute__((ext_vector_type(16)));
typedef short s16x4  __attribute__((ext_vector_type(4)));
typedef short s16x8  __attribute__((ext_vector_type(8)));

static __device__ __forceinline__ short f2bf(float f) {
    union { float f; unsigned u; } x; x.f = f;
    unsigned r = x.u + 0x7FFFu + ((x.u >> 16) & 1u);
    return (short)(r >> 16);
}
static __device__ __forceinline__ s16x8 pack8(float4 lo, float4 hi) {
    s16x8 r;
    r[0]=f2bf(lo.x); r[1]=f2bf(lo.y); r[2]=f2bf(lo.z); r[3]=f2bf(lo.w);
    r[4]=f2bf(hi.x); r[5]=f2bf(hi.y); r[6]=f2bf(hi.z); r[7]=f2bf(hi.w);
    return r;
}
static __device__ __forceinline__ unsigned cvtpk(float a, float b) {
    unsigned r;
    asm("v_cvt_pk_bf16_f32 %0, %1, %2" : "=v"(r) : "v"(a), "v"(b));
    return r;
}
static __device__ __forceinline__ void gld16(short* l, const short* g) {
    __builtin_amdgcn_global_load_lds(
        (const __attribute__((address_space(1))) void*)g,
        (__attribute__((address_space(3))) void*)l, 16, 0, 0);
}

#define MFMA32(A,B,C) __builtin_amdgcn_mfma_f32_32x32x16_bf16(A, B, C, 0, 0, 0)
#define MFMA16(A,B,C) __builtin_amdgcn_mfma_f32_16x16x32_bf16(A, B, C, 0, 0, 0)

struct PA { s16x8 a, b; };
// P (lane's 32 keys for its q-col) -> two bf16 A-fragments (T12; proven r2-r13)
static __device__ __forceinline__ PA packP(const f32x16& s) {
    PA r;
    unsigned A0 = cvtpk(s[0], s[1]),  A1 = cvtpk(s[2], s[3]);
    unsigned B0 = cvtpk(s[4], s[5]),  B1 = cvtpk(s[6], s[7]);
    asm volatile("v_permlane32_swap_b32 %0, %1" : "+v"(A0), "+v"(B0));
    asm volatile("v_permlane32_swap_b32 %0, %1" : "+v"(A1), "+v"(B1));
    union { s16x8 v; unsigned u[4]; } w;
    w.u[0]=A0; w.u[1]=A1; w.u[2]=B0; w.u[3]=B1;
    r.a = w.v;
    unsigned C0 = cvtpk(s[8], s[9]),   C1 = cvtpk(s[10], s[11]);
    unsigned D0 = cvtpk(s[12], s[13]), D1 = cvtpk(s[14], s[15]);
    asm volatile("v_permlane32_swap_b32 %0, %1" : "+v"(C0), "+v"(D0));
    asm volatile("v_permlane32_swap_b32 %0, %1" : "+v"(C1), "+v"(D1));
    union { s16x8 v; unsigned u[4]; } w2;
    w2.u[0]=C0; w2.u[1]=C1; w2.u[2]=D0; w2.u[3]=D1;
    r.b = w2.v;
    return r;
}
static __device__ __forceinline__ float tree_max(const f32x16& s) {
    float t[8];
    #pragma unroll
    for (int i = 0; i < 8; i++) t[i] = fmaxf(s[i], s[i+8]);
    #pragma unroll
    for (int i = 0; i < 4; i++) t[i] = fmaxf(t[i], t[i+4]);
    return fmaxf(fmaxf(t[0], t[2]), fmaxf(t[1], t[3]));
}
static __device__ __forceinline__ float tree_sum(const f32x16& s) {
    float t[8];
    #pragma unroll
    for (int i = 0; i < 8; i++) t[i] = s[i] + s[i+8];
    #pragma unroll
    for (int i = 0; i < 4; i++) t[i] += t[i+4];
    return (t[0] + t[2]) + (t[1] + t[3]);
}

// ---------------------------------------------------------------------------
// fp32 -> bf16 conversion for x, W_qkv, W_proj (one pass, vectorized)
// ---------------------------------------------------------------------------
__global__ __launch_bounds__(256) void convert3(
    const float* __restrict__ x, const float* __restrict__ wq,
    const float* __restrict__ wp,
    short* __restrict__ xb, short* __restrict__ wqb, short* __restrict__ wpb)
{
    const int idx = blockIdx.x * 256 + threadIdx.x;   // one 8-elem chunk
    const int C1 = 4194304/8, C2 = 3145728/8;
    const float* src; short* dst; int off;
    if (idx < C1)            { src = x;  dst = xb;  off = idx; }
    else if (idx < C1 + C2)  { src = wq; dst = wqb; off = idx - C1; }
    else                     { src = wp; dst = wpb; off = idx - C1 - C2; }
    float4 a = ((const float4*)src)[off*2];
    float4 b = ((const float4*)src)[off*2 + 1];
    ((s16x8*)dst)[off] = pack8(a, b);
}

// ---------------------------------------------------------------------------
// bf16 GEMM, m97 structure: 128x128 tile, BK=64, global_load_lds staging,
// XCD-aware bijective block swizzle (T1; nwg%8==0 for both grids).
// MODE 0: fused per-head LayerNorm on q/k; q row-major; K/V written directly
//         in MFMA-fragment order (KP/VP). MODE 1: bias add, fp32 out.
// ---------------------------------------------------------------------------
#define BKG 64

template<int MODE>
__global__ __launch_bounds__(256) void gemm_bf16(
    const short* __restrict__ A, const short* __restrict__ W,
    const float* __restrict__ bias,
    const float* __restrict__ qg, const float* __restrict__ qbeta,
    const float* __restrict__ kg, const float* __restrict__ kbeta,
    short* __restrict__ qb, short* __restrict__ kpb, short* __restrict__ vpb,
    float* __restrict__ out)
{
    alignas(16) __shared__ short As[128*BKG];
    alignas(16) __shared__ short Bs[128*BKG];
    const int tid  = threadIdx.x;
    const int lane = tid & 63, wave = tid >> 6;
    const int wr = wave >> 1, wc = wave & 1;
    const int c = lane & 15, g = lane >> 4;

    // XCD-aware bijective swizzle: contiguous tile chunk per XCD (T1)
    const int nwg = gridDim.x * gridDim.y;            // 768 (MODE 0) / 256 (MODE 1); %8==0
    const int cpx = nwg >> 3;
    const int flat = blockIdx.y * gridDim.x + blockIdx.x;
    const int swz = (flat & 7) * cpx + (flat >> 3);
    const int bx = swz % gridDim.x, by = swz / gridDim.x;
    const int brow = by * 128, bcol = bx * 128;

    const int srow = lane >> 3;
    const int scol = (lane & 7) * 8;
    const short* ag = A + (size_t)(brow + srow)*DIM + scol;
    const short* wg = W + (size_t)(bcol + srow)*DIM + scol;

    f32x4 acc[4][4] = {};

    for (int k0 = 0; k0 < DIM; k0 += BKG) {
        #pragma unroll
        for (int j = 0; j < 4; j++) {
            const int rg = (wave*4 + j) * 8;
            gld16(&As[rg*BKG], ag + (size_t)rg*DIM + k0);
            gld16(&Bs[rg*BKG], wg + (size_t)rg*DIM + k0);
        }
        __syncthreads();

        #pragma unroll
        for (int ks = 0; ks < 2; ks++) {
            s16x8 af[4], bf[4];
            #pragma unroll
            for (int m = 0; m < 4; m++)
                af[m] = *(const s16x8*)&As[(wr*64 + m*16 + c)*BKG + ks*32 + g*8];
            #pragma unroll
            for (int n = 0; n < 4; n++)
                bf[n] = *(const s16x8*)&Bs[(wc*64 + n*16 + c)*BKG + ks*32 + g*8];
            #pragma unroll
            for (int m = 0; m < 4; m++)
                #pragma unroll
                for (int n = 0; n < 4; n++)
                    acc[m][n] = MFMA16(af[m], bf[n], acc[m][n]);
        }
        __syncthreads();
    }

    if (MODE == 0) {
        const int colbase = bcol + wc*64;
        const int t = colbase >> 10;               // 0:q 1:k 2:v
        const int h = (colbase >> 6) & 15;
        float gam[4], bet[4];
        float scale = 1.0f;
        if (t < 2) {
            const float* G  = (t == 0) ? qg : kg;
            const float* Bt = (t == 0) ? qbeta : kbeta;
            #pragma unroll
            for (int n = 0; n < 4; n++) { gam[n] = G[n*16 + c]; bet[n] = Bt[n*16 + c]; }
            if (t == 0) scale = 0.125f * 1.44269504088896340736f;  // D^-0.5 * log2e
        }
        #pragma unroll
        for (int m = 0; m < 4; m++) {
            #pragma unroll
            for (int j = 0; j < 4; j++) {
                const int row = brow + wr*64 + m*16 + g*4 + j;
                const int bi = row >> 11, ni = row & (SEQ-1);
                const int bh = bi*HEADS + h;
                float v0 = acc[m][0][j], v1 = acc[m][1][j];
                float v2 = acc[m][2][j], v3 = acc[m][3][j];
                if (t < 2) {
                    float s = (v0 + v1) + (v2 + v3);
                    s += __shfl_xor(s, 1); s += __shfl_xor(s, 2);
                    s += __shfl_xor(s, 4); s += __shfl_xor(s, 8);
                    const float mu = s * 0.015625f;
                    v0 -= mu; v1 -= mu; v2 -= mu; v3 -= mu;
                    float vv = (v0*v0 + v1*v1) + (v2*v2 + v3*v3);
                    vv += __shfl_xor(vv, 1); vv += __shfl_xor(vv, 2);
                    vv += __shfl_xor(vv, 4); vv += __shfl_xor(vv, 8);
                    const float rstd = rsqrtf(vv * 0.015625f + EPS);
                    v0 = (v0*rstd*gam[0] + bet[0]) * scale;
                    v1 = (v1*rstd*gam[1] + bet[1]) * scale;
                    v2 = (v2*rstd*gam[2] + bet[2]) * scale;
                    v3 = (v3*rstd*gam[3] + bet[3]) * scale;
                }
                if (t == 0) {
                    const size_t rb = ((size_t)bh*SEQ + ni)*HD;
                    qb[rb + 0*16 + c] = f2bf(v0);
                    qb[rb + 1*16 + c] = f2bf(v1);
                    qb[rb + 2*16 + c] = f2bf(v2);
                    qb[rb + 3*16 + c] = f2bf(v3);
                } else {
                    const size_t tb = ((size_t)bh*64 + (ni >> 5)) * 2048;
                    const int kl = ni & 31;
                    if (t == 1) {
                        const size_t b2 = tb + (size_t)(((c >> 3)*32 + kl)*8 + (c & 7));
                        kpb[b2 + 0*512] = f2bf(v0);
                        kpb[b2 + 1*512] = f2bf(v1);
                        kpb[b2 + 2*512] = f2bf(v2);
                        kpb[b2 + 3*512] = f2bf(v3);
                    } else {
                        const int hi2 = (kl & 15) >> 3, e2 = kl & 7;
                        const size_t b0 = tb + (size_t)((2*(kl >> 4))*512 + (hi2*32)*8 + e2);
                        vpb[b0 + (size_t)(c)*8]        = f2bf(v0);
                        vpb[b0 + (size_t)(16 + c)*8]   = f2bf(v1);
                        vpb[b0 + 512 + (size_t)(c)*8]      = f2bf(v2);
                        vpb[b0 + 512 + (size_t)(16 + c)*8] = f2bf(v3);
                    }
                }
            }
        }
    } else {
        #pragma unroll
        for (int n = 0; n < 4; n++) {
            const int col = bcol + wc*64 + n*16 + c;
            const float bv = bias[col];
            #pragma unroll
            for (int m = 0; m < 4; m++) {
                #pragma unroll
                for (int j = 0; j < 4; j++) {
                    const int row = brow + wr*64 + m*16 + g*4 + j;
                    out[(size_t)row*DIM + col] = acc[m][n][j] + bv;
                }
            }
        }
    }
}

// ---------------------------------------------------------------------------
// Flash attention: r13 exact (q32/wave, 2-way split-K, launch_bounds(256,4),
// single kc/vc banks, shfl_xor reduces, exp2f, T12/T13, 2-way LDS merge).
// r14's depth-2 pipeline + deferred sum reverted (regressed: L1 thrash,
// FETCH +37%).
// ---------------------------------------------------------------------------
__global__ __launch_bounds__(256, 4) void attn_kernel(
    const short* __restrict__ qbuf, const short* __restrict__ KP,
    const short* __restrict__ VP, short* __restrict__ aout)
{
    alignas(16) __shared__ float OL[2][64][32];   // [qsub][lane][reg]
    __shared__ float ML[2][2][64];                // [qsub][{m,l}][lane]

    const int bh = blockIdx.x, qt = blockIdx.y;
    const int tid = threadIdx.x, wave = tid >> 6, lane = tid & 63;
    const int qsub = wave >> 1, half = wave & 1;
    const int l31 = lane & 31, hi = lane >> 5;
    const int q0 = qt*64 + qsub*32;

    s16x8 qf[4];
    const short* qrow = qbuf + ((size_t)bh*SEQ + q0 + l31)*HD + 8*hi;
    #pragma unroll
    for (int ks = 0; ks < 4; ks++) qf[ks] = *(const s16x8*)(qrow + 16*ks);

    const short* kp = KP + ((size_t)bh*64 + half*32)*2048 + lane*8;
    const short* vp = VP + ((size_t)bh*64 + half*32)*2048 + lane*8;

    // prologue: tile 0 of this wave's K-half
    s16x8 kc0 = *(const s16x8*)(kp);
    s16x8 kc1 = *(const s16x8*)(kp + 512);
    s16x8 kc2 = *(const s16x8*)(kp + 1024);
    s16x8 kc3 = *(const s16x8*)(kp + 1536);
    s16x8 vc0 = *(const s16x8*)(vp);
    s16x8 vc1 = *(const s16x8*)(vp + 512);
    s16x8 vc2 = *(const s16x8*)(vp + 1024);
    s16x8 vc3 = *(const s16x8*)(vp + 1536);

    f32x16 o0 = {}, o1 = {};
    float m = -1e30f, l = 0.f;

    for (int it = 0; it < 32; it++) {
        // S^T = K*Q : lane holds 16 keys for q = q0+l31
        f32x16 s = {};
        __builtin_amdgcn_s_setprio(1);
        s = MFMA32(kc0, qf[0], s);
        s = MFMA32(kc1, qf[1], s);
        s = MFMA32(kc2, qf[2], s);
        s = MFMA32(kc3, qf[3], s);
        __builtin_amdgcn_s_setprio(0);

        // reload kc for next tile NOW (covered by softmax + PV below)
        const int nt = ((it + 1) & 31) * 2048;
        kc0 = *(const s16x8*)(kp + nt);
        kc1 = *(const s16x8*)(kp + nt + 512);
        kc2 = *(const s16x8*)(kp + nt + 1024);
        kc3 = *(const s16x8*)(kp + nt + 1536);
        __builtin_amdgcn_sched_barrier(0);

        // softmax (r13 exact)
        float pmax = tree_max(s);
        pmax = fmaxf(pmax, __shfl_xor(pmax, 32));

        if (!__all(pmax - m <= 8.0f)) {           // defer-max (T13)
            float mn = fmaxf(m, pmax);
            float corr = exp2f(m - mn);
            #pragma unroll
            for (int i = 0; i < 16; i++) { o0[i] *= corr; o1[i] *= corr; }
            l *= corr;
            m = mn;
        }
        #pragma unroll
        for (int i = 0; i < 16; i++) s[i] = exp2f(s[i] - m);
        float rs = tree_sum(s);
        rs += __shfl_xor(rs, 32);
        l += rs;

        // P -> bf16 A-fragments (T12)
        PA pa = packP(s);

        // O^T += V^T * P
        __builtin_amdgcn_s_setprio(1);
        o0 = MFMA32(vc0, pa.a, o0);
        o1 = MFMA32(vc1, pa.a, o1);
        o0 = MFMA32(vc2, pa.b, o0);
        o1 = MFMA32(vc3, pa.b, o1);
        __builtin_amdgcn_s_setprio(0);

        // reload vc for next tile (covered by next iter's S phase + softmax)
        vc0 = *(const s16x8*)(vp + nt);
        vc1 = *(const s16x8*)(vp + nt + 512);
        vc2 = *(const s16x8*)(vp + nt + 1024);
        vc3 = *(const s16x8*)(vp + nt + 1536);
    }

    // ---- merge the two K-halves (r13 exact) ----
    if (half == 1) {
        float* ob = &OL[qsub][lane][0];
        #pragma unroll
        for (int i = 0; i < 8; i++) {
            const int slot = (i + (lane & 7)) & 7;
            f32x4 v;
            if (i < 4) { v[0]=o0[4*i]; v[1]=o0[4*i+1]; v[2]=o0[4*i+2]; v[3]=o0[4*i+3]; }
            else { const int j = i-4; v[0]=o1[4*j]; v[1]=o1[4*j+1]; v[2]=o1[4*j+2]; v[3]=o1[4*j+3]; }
            *(f32x4*)(ob + slot*4) = v;
        }
        ML[qsub][0][lane] = m;
        ML[qsub][1][lane] = l;
    }
    __syncthreads();
    if (half == 0) {
        const float m1 = ML[qsub][0][lane];
        const float l1 = ML[qsub][1][lane];
        const float ms = fmaxf(m, m1);
        const float c0 = exp2f(m - ms), c1 = exp2f(m1 - ms);
        const float inv = 1.0f / (l*c0 + l1*c1);
        const float* ob = &OL[qsub][lane][0];
        const int b = bh >> 4, h = bh & 15;
        short* dst = aout + ((size_t)(b*SEQ + q0 + l31))*DIM + h*HD;
        #pragma unroll
        for (int i = 0; i < 8; i++) {
            const int slot = (i + (lane & 7)) & 7;
            f32x4 p = *(const f32x4*)(ob + slot*4);
            s16x4 st;
            if (i < 4) {
                #pragma unroll
                for (int j = 0; j < 4; j++) st[j] = f2bf((o0[4*i+j]*c0 + p[j]*c1) * inv);
                *(s16x4*)(dst + 8*i + 4*hi) = st;
            } else {
                const int t3 = i - 4;
                #pragma unroll
                for (int j = 0; j < 4; j++) st[j] = f2bf((o1[4*t3+j]*c0 + p[j]*c1) * inv);
                *(s16x4*)(dst + 32 + 8*t3 + 4*hi) = st;
            }
        }
    }
}

// ---------------------------------------------------------------------------
extern "C" void kernel_launch(void* const* d_in, const int* in_sizes, int n_in,
                              void* d_out, int out_size, void* d_ws, size_t ws_size,
                              hipStream_t stream)
{
    const float* x     = (const float*)d_in[0];
    const float* Wqkv  = (const float*)d_in[1];
    const float* qg    = (const float*)d_in[2];
    const float* qbeta = (const float*)d_in[3];
    const float* kg    = (const float*)d_in[4];
    const float* kbeta = (const float*)d_in[5];
    const float* Wproj = (const float*)d_in[6];
    const float* bproj = (const float*)d_in[7];
    float* out = (float*)d_out;

    char* ws = (char*)d_ws;
    const size_t MB = 1024*1024;
    short* xb     = (short*)(ws);              // 8 MB; dead after gemm<0>
    short* aout   = (short*)(ws);              // reuses xb slot (written by attn)
    short* wqkvb  = (short*)(ws + 8*MB);       // 6 MB
    short* wprojb = (short*)(ws + 14*MB);      // 2 MB (live until gemm<1>)
    short* q      = (short*)(ws + 16*MB);      // 8 MB
    short* KP     = (short*)(ws + 24*MB);      // 8 MB (fragment-order K)
    short* VP     = (short*)(ws + 32*MB);      // 8 MB (fragment-order V)

    // 1. fp32 -> bf16 conversions
    convert3<<<dim3(4096), 256, 0, stream>>>(x, Wqkv, Wproj, xb, wqkvb, wprojb);

    // 2. QKV GEMM + fused q/k LayerNorm + fused K/V fragment repack
    gemm_bf16<0><<<dim3(3*DIM/128, ROWS/128), 256, 0, stream>>>(
        xb, wqkvb, nullptr, qg, qbeta, kg, kbeta, q, KP, VP, nullptr);

    // 3. Flash attention (q32/wave, 2-way split-K, r13-exact)
    attn_kernel<<<dim3(BATCH*HEADS, SEQ/64), 256, 0, stream>>>(q, KP, VP, aout);

    // 4. Projection GEMM + bias -> fp32 d_out
    gemm_bf16<1><<<dim3(DIM/128, ROWS/128), 256, 0, stream>>>(
        aout, wprojb, bproj, nullptr, nullptr, nullptr, nullptr,
        nullptr, nullptr, nullptr, out);
}

// Round 16
// 137.423 us; speedup vs baseline: 1.0868x; 1.0092x over previous
//
#include <hip/hip_runtime.h>

#define DIM 1024
#define HEADS 16
#define HD 64
#define BATCH 2
#define SEQ 2048
#define ROWS (BATCH*SEQ)          // 4096
#define EPS 1e-6f

typedef float f32x4  __attribute__((ext_vector_type(4)));
typedef float f32x16 __attribute__((ext_vector_type(16)));
typedef short s16x4  __attribute__((ext_vector_type(4)));
typedef short s16x8  __attribute__((ext_vector_type(8)));

static __device__ __forceinline__ short f2bf(float f) {
    union { float f; unsigned u; } x; x.f = f;
    unsigned r = x.u + 0x7FFFu + ((x.u >> 16) & 1u);
    return (short)(r >> 16);
}
static __device__ __forceinline__ s16x8 pack8(float4 lo, float4 hi) {
    s16x8 r;
    r[0]=f2bf(lo.x); r[1]=f2bf(lo.y); r[2]=f2bf(lo.z); r[3]=f2bf(lo.w);
    r[4]=f2bf(hi.x); r[5]=f2bf(hi.y); r[6]=f2bf(hi.z); r[7]=f2bf(hi.w);
    return r;
}
static __device__ __forceinline__ unsigned cvtpk(float a, float b) {
    unsigned r;
    asm("v_cvt_pk_bf16_f32 %0, %1, %2" : "=v"(r) : "v"(a), "v"(b));
    return r;
}
static __device__ __forceinline__ void gld16(short* l, const short* g) {
    __builtin_amdgcn_global_load_lds(
        (const __attribute__((address_space(1))) void*)g,
        (__attribute__((address_space(3))) void*)l, 16, 0, 0);
}

#define MFMA32(A,B,C) __builtin_amdgcn_mfma_f32_32x32x16_bf16(A, B, C, 0, 0, 0)
#define MFMA16(A,B,C) __builtin_amdgcn_mfma_f32_16x16x32_bf16(A, B, C, 0, 0, 0)

struct PA { s16x8 a, b; };
// P (lane's 32 keys for its q-col) -> two bf16 A-fragments (T12; proven r2-r15)
static __device__ __forceinline__ PA packP(const f32x16& s) {
    PA r;
    unsigned A0 = cvtpk(s[0], s[1]),  A1 = cvtpk(s[2], s[3]);
    unsigned B0 = cvtpk(s[4], s[5]),  B1 = cvtpk(s[6], s[7]);
    asm volatile("v_permlane32_swap_b32 %0, %1" : "+v"(A0), "+v"(B0));
    asm volatile("v_permlane32_swap_b32 %0, %1" : "+v"(A1), "+v"(B1));
    union { s16x8 v; unsigned u[4]; } w;
    w.u[0]=A0; w.u[1]=A1; w.u[2]=B0; w.u[3]=B1;
    r.a = w.v;
    unsigned C0 = cvtpk(s[8], s[9]),   C1 = cvtpk(s[10], s[11]);
    unsigned D0 = cvtpk(s[12], s[13]), D1 = cvtpk(s[14], s[15]);
    asm volatile("v_permlane32_swap_b32 %0, %1" : "+v"(C0), "+v"(D0));
    asm volatile("v_permlane32_swap_b32 %0, %1" : "+v"(C1), "+v"(D1));
    union { s16x8 v; unsigned u[4]; } w2;
    w2.u[0]=C0; w2.u[1]=C1; w2.u[2]=D0; w2.u[3]=D1;
    r.b = w2.v;
    return r;
}
static __device__ __forceinline__ float tree_max(const f32x16& s) {
    float t[8];
    #pragma unroll
    for (int i = 0; i < 8; i++) t[i] = fmaxf(s[i], s[i+8]);
    #pragma unroll
    for (int i = 0; i < 4; i++) t[i] = fmaxf(t[i], t[i+4]);
    return fmaxf(fmaxf(t[0], t[2]), fmaxf(t[1], t[3]));
}
static __device__ __forceinline__ float tree_sum(const f32x16& s) {
    float t[8];
    #pragma unroll
    for (int i = 0; i < 8; i++) t[i] = s[i] + s[i+8];
    #pragma unroll
    for (int i = 0; i < 4; i++) t[i] += t[i+4];
    return (t[0] + t[2]) + (t[1] + t[3]);
}

// ---------------------------------------------------------------------------
// fp32 -> bf16 conversion for x, W_qkv, W_proj (one pass, vectorized)
// ---------------------------------------------------------------------------
__global__ __launch_bounds__(256) void convert3(
    const float* __restrict__ x, const float* __restrict__ wq,
    const float* __restrict__ wp,
    short* __restrict__ xb, short* __restrict__ wqb, short* __restrict__ wpb)
{
    const int idx = blockIdx.x * 256 + threadIdx.x;   // one 8-elem chunk
    const int C1 = 4194304/8, C2 = 3145728/8;
    const float* src; short* dst; int off;
    if (idx < C1)            { src = x;  dst = xb;  off = idx; }
    else if (idx < C1 + C2)  { src = wq; dst = wqb; off = idx - C1; }
    else                     { src = wp; dst = wpb; off = idx - C1 - C2; }
    float4 a = ((const float4*)src)[off*2];
    float4 b = ((const float4*)src)[off*2 + 1];
    ((s16x8*)dst)[off] = pack8(a, b);
}

// ---------------------------------------------------------------------------
// bf16 GEMM, m97 structure: 128x128 tile, BK=64, global_load_lds staging,
// XCD-aware bijective block swizzle (T1; nwg%8==0 for both grids).
// MODE 0: fused per-head LayerNorm on q/k; q row-major; K/V written directly
//         in MFMA-fragment order (KP/VP). MODE 1: bias add, fp32 out.
// ---------------------------------------------------------------------------
#define BKG 64

template<int MODE>
__global__ __launch_bounds__(256) void gemm_bf16(
    const short* __restrict__ A, const short* __restrict__ W,
    const float* __restrict__ bias,
    const float* __restrict__ qg, const float* __restrict__ qbeta,
    const float* __restrict__ kg, const float* __restrict__ kbeta,
    short* __restrict__ qb, short* __restrict__ kpb, short* __restrict__ vpb,
    float* __restrict__ out)
{
    alignas(16) __shared__ short As[128*BKG];
    alignas(16) __shared__ short Bs[128*BKG];
    const int tid  = threadIdx.x;
    const int lane = tid & 63, wave = tid >> 6;
    const int wr = wave >> 1, wc = wave & 1;
    const int c = lane & 15, g = lane >> 4;

    // XCD-aware bijective swizzle: contiguous tile chunk per XCD (T1)
    const int nwg = gridDim.x * gridDim.y;            // 768 / 256; %8==0
    const int cpx = nwg >> 3;
    const int flat = blockIdx.y * gridDim.x + blockIdx.x;
    const int swz = (flat & 7) * cpx + (flat >> 3);
    const int bx = swz % gridDim.x, by = swz / gridDim.x;
    const int brow = by * 128, bcol = bx * 128;

    const int srow = lane >> 3;
    const int scol = (lane & 7) * 8;
    const short* ag = A + (size_t)(brow + srow)*DIM + scol;
    const short* wg = W + (size_t)(bcol + srow)*DIM + scol;

    f32x4 acc[4][4] = {};

    for (int k0 = 0; k0 < DIM; k0 += BKG) {
        #pragma unroll
        for (int j = 0; j < 4; j++) {
            const int rg = (wave*4 + j) * 8;
            gld16(&As[rg*BKG], ag + (size_t)rg*DIM + k0);
            gld16(&Bs[rg*BKG], wg + (size_t)rg*DIM + k0);
        }
        __syncthreads();

        #pragma unroll
        for (int ks = 0; ks < 2; ks++) {
            s16x8 af[4], bf[4];
            #pragma unroll
            for (int m = 0; m < 4; m++)
                af[m] = *(const s16x8*)&As[(wr*64 + m*16 + c)*BKG + ks*32 + g*8];
            #pragma unroll
            for (int n = 0; n < 4; n++)
                bf[n] = *(const s16x8*)&Bs[(wc*64 + n*16 + c)*BKG + ks*32 + g*8];
            #pragma unroll
            for (int m = 0; m < 4; m++)
                #pragma unroll
                for (int n = 0; n < 4; n++)
                    acc[m][n] = MFMA16(af[m], bf[n], acc[m][n]);
        }
        __syncthreads();
    }

    if (MODE == 0) {
        const int colbase = bcol + wc*64;
        const int t = colbase >> 10;               // 0:q 1:k 2:v
        const int h = (colbase >> 6) & 15;
        float gam[4], bet[4];
        float scale = 1.0f;
        if (t < 2) {
            const float* G  = (t == 0) ? qg : kg;
            const float* Bt = (t == 0) ? qbeta : kbeta;
            #pragma unroll
            for (int n = 0; n < 4; n++) { gam[n] = G[n*16 + c]; bet[n] = Bt[n*16 + c]; }
            if (t == 0) scale = 0.125f * 1.44269504088896340736f;  // D^-0.5 * log2e
        }
        #pragma unroll
        for (int m = 0; m < 4; m++) {
            #pragma unroll
            for (int j = 0; j < 4; j++) {
                const int row = brow + wr*64 + m*16 + g*4 + j;
                const int bi = row >> 11, ni = row & (SEQ-1);
                const int bh = bi*HEADS + h;
                float v0 = acc[m][0][j], v1 = acc[m][1][j];
                float v2 = acc[m][2][j], v3 = acc[m][3][j];
                if (t < 2) {
                    float s = (v0 + v1) + (v2 + v3);
                    s += __shfl_xor(s, 1); s += __shfl_xor(s, 2);
                    s += __shfl_xor(s, 4); s += __shfl_xor(s, 8);
                    const float mu = s * 0.015625f;
                    v0 -= mu; v1 -= mu; v2 -= mu; v3 -= mu;
                    float vv = (v0*v0 + v1*v1) + (v2*v2 + v3*v3);
                    vv += __shfl_xor(vv, 1); vv += __shfl_xor(vv, 2);
                    vv += __shfl_xor(vv, 4); vv += __shfl_xor(vv, 8);
                    const float rstd = rsqrtf(vv * 0.015625f + EPS);
                    v0 = (v0*rstd*gam[0] + bet[0]) * scale;
                    v1 = (v1*rstd*gam[1] + bet[1]) * scale;
                    v2 = (v2*rstd*gam[2] + bet[2]) * scale;
                    v3 = (v3*rstd*gam[3] + bet[3]) * scale;
                }
                if (t == 0) {
                    const size_t rb = ((size_t)bh*SEQ + ni)*HD;
                    qb[rb + 0*16 + c] = f2bf(v0);
                    qb[rb + 1*16 + c] = f2bf(v1);
                    qb[rb + 2*16 + c] = f2bf(v2);
                    qb[rb + 3*16 + c] = f2bf(v3);
                } else {
                    const size_t tb = ((size_t)bh*64 + (ni >> 5)) * 2048;
                    const int kl = ni & 31;
                    if (t == 1) {
                        const size_t b2 = tb + (size_t)(((c >> 3)*32 + kl)*8 + (c & 7));
                        kpb[b2 + 0*512] = f2bf(v0);
                        kpb[b2 + 1*512] = f2bf(v1);
                        kpb[b2 + 2*512] = f2bf(v2);
                        kpb[b2 + 3*512] = f2bf(v3);
                    } else {
                        const int hi2 = (kl & 15) >> 3, e2 = kl & 7;
                        const size_t b0 = tb + (size_t)((2*(kl >> 4))*512 + (hi2*32)*8 + e2);
                        vpb[b0 + (size_t)(c)*8]        = f2bf(v0);
                        vpb[b0 + (size_t)(16 + c)*8]   = f2bf(v1);
                        vpb[b0 + 512 + (size_t)(c)*8]      = f2bf(v2);
                        vpb[b0 + 512 + (size_t)(16 + c)*8] = f2bf(v3);
                    }
                }
            }
        }
    } else {
        #pragma unroll
        for (int n = 0; n < 4; n++) {
            const int col = bcol + wc*64 + n*16 + c;
            const float bv = bias[col];
            #pragma unroll
            for (int m = 0; m < 4; m++) {
                #pragma unroll
                for (int j = 0; j < 4; j++) {
                    const int row = brow + wr*64 + m*16 + g*4 + j;
                    out[(size_t)row*DIM + col] = acc[m][n][j] + bv;
                }
            }
        }
    }
}

// ---------------------------------------------------------------------------
// Flash attention: r15 structure (q32/wave, 2-way split-K, launch_bounds
// (256,4), single kc/vc banks, exp2f, T12/T13, 2-way LDS merge) with the
// steady-state softmax made shuffle-free:
//  - T13 vote uses LANE-LOCAL pmax (__all over 64 lanes == per-row check,
//    since each row's max is the max of its two mirror lanes) -> the
//    cross-half max shuffle moves into the rare wave-uniform slow path;
//  - l accumulates per half-lane (m is mirror-identical, so corr factors
//    match); one deferred __shfl_xor(l,32) after the loop. Exact.
// ---------------------------------------------------------------------------
__global__ __launch_bounds__(256, 4) void attn_kernel(
    const short* __restrict__ qbuf, const short* __restrict__ KP,
    const short* __restrict__ VP, short* __restrict__ aout)
{
    alignas(16) __shared__ float OL[2][64][32];   // [qsub][lane][reg]
    __shared__ float ML[2][2][64];                // [qsub][{m,l}][lane]

    const int bh = blockIdx.x, qt = blockIdx.y;
    const int tid = threadIdx.x, wave = tid >> 6, lane = tid & 63;
    const int qsub = wave >> 1, half = wave & 1;
    const int l31 = lane & 31, hi = lane >> 5;
    const int q0 = qt*64 + qsub*32;

    s16x8 qf[4];
    const short* qrow = qbuf + ((size_t)bh*SEQ + q0 + l31)*HD + 8*hi;
    #pragma unroll
    for (int ks = 0; ks < 4; ks++) qf[ks] = *(const s16x8*)(qrow + 16*ks);

    const short* kp = KP + ((size_t)bh*64 + half*32)*2048 + lane*8;
    const short* vp = VP + ((size_t)bh*64 + half*32)*2048 + lane*8;

    // prologue: tile 0 of this wave's K-half
    s16x8 kc0 = *(const s16x8*)(kp);
    s16x8 kc1 = *(const s16x8*)(kp + 512);
    s16x8 kc2 = *(const s16x8*)(kp + 1024);
    s16x8 kc3 = *(const s16x8*)(kp + 1536);
    s16x8 vc0 = *(const s16x8*)(vp);
    s16x8 vc1 = *(const s16x8*)(vp + 512);
    s16x8 vc2 = *(const s16x8*)(vp + 1024);
    s16x8 vc3 = *(const s16x8*)(vp + 1536);

    f32x16 o0 = {}, o1 = {};
    float m = -1e30f, l = 0.f;

    for (int it = 0; it < 32; it++) {
        // S^T = K*Q : lane holds 16 keys for q = q0+l31
        f32x16 s = {};
        __builtin_amdgcn_s_setprio(1);
        s = MFMA32(kc0, qf[0], s);
        s = MFMA32(kc1, qf[1], s);
        s = MFMA32(kc2, qf[2], s);
        s = MFMA32(kc3, qf[3], s);
        __builtin_amdgcn_s_setprio(0);

        // reload kc for next tile NOW (covered by softmax + PV below)
        const int nt = ((it + 1) & 31) * 2048;
        kc0 = *(const s16x8*)(kp + nt);
        kc1 = *(const s16x8*)(kp + nt + 512);
        kc2 = *(const s16x8*)(kp + nt + 1024);
        kc3 = *(const s16x8*)(kp + nt + 1536);
        __builtin_amdgcn_sched_barrier(0);

        // softmax: shuffle-free fast path (T13 vote on lane-local max)
        float pmax = tree_max(s);
        if (!__all(pmax - m <= 8.0f)) {           // rare, wave-uniform
            pmax = fmaxf(pmax, __shfl_xor(pmax, 32));   // true row max
            float mn = fmaxf(m, pmax);
            float corr = exp2f(m - mn);
            #pragma unroll
            for (int i = 0; i < 16; i++) { o0[i] *= corr; o1[i] *= corr; }
            l *= corr;
            m = mn;
        }
        #pragma unroll
        for (int i = 0; i < 16; i++) s[i] = exp2f(s[i] - m);
        l += tree_sum(s);                         // per half-lane partial

        // P -> bf16 A-fragments (T12)
        PA pa = packP(s);

        // O^T += V^T * P
        __builtin_amdgcn_s_setprio(1);
        o0 = MFMA32(vc0, pa.a, o0);
        o1 = MFMA32(vc1, pa.a, o1);
        o0 = MFMA32(vc2, pa.b, o0);
        o1 = MFMA32(vc3, pa.b, o1);
        __builtin_amdgcn_s_setprio(0);

        // reload vc for next tile (covered by next iter's S phase + softmax)
        vc0 = *(const s16x8*)(vp + nt);
        vc1 = *(const s16x8*)(vp + nt + 512);
        vc2 = *(const s16x8*)(vp + nt + 1024);
        vc3 = *(const s16x8*)(vp + nt + 1536);
    }

    // deferred cross-half sum (exact: m mirror-identical throughout)
    l += __shfl_xor(l, 32);

    // ---- merge the two K-halves (r15 exact) ----
    if (half == 1) {
        float* ob = &OL[qsub][lane][0];
        #pragma unroll
        for (int i = 0; i < 8; i++) {
            const int slot = (i + (lane & 7)) & 7;
            f32x4 v;
            if (i < 4) { v[0]=o0[4*i]; v[1]=o0[4*i+1]; v[2]=o0[4*i+2]; v[3]=o0[4*i+3]; }
            else { const int j = i-4; v[0]=o1[4*j]; v[1]=o1[4*j+1]; v[2]=o1[4*j+2]; v[3]=o1[4*j+3]; }
            *(f32x4*)(ob + slot*4) = v;
        }
        ML[qsub][0][lane] = m;
        ML[qsub][1][lane] = l;
    }
    __syncthreads();
    if (half == 0) {
        const float m1 = ML[qsub][0][lane];
        const float l1 = ML[qsub][1][lane];
        const float ms = fmaxf(m, m1);
        const float c0 = exp2f(m - ms), c1 = exp2f(m1 - ms);
        const float inv = 1.0f / (l*c0 + l1*c1);
        const float* ob = &OL[qsub][lane][0];
        const int b = bh >> 4, h = bh & 15;
        short* dst = aout + ((size_t)(b*SEQ + q0 + l31))*DIM + h*HD;
        #pragma unroll
        for (int i = 0; i < 8; i++) {
            const int slot = (i + (lane & 7)) & 7;
            f32x4 p = *(const f32x4*)(ob + slot*4);
            s16x4 st;
            if (i < 4) {
                #pragma unroll
                for (int j = 0; j < 4; j++) st[j] = f2bf((o0[4*i+j]*c0 + p[j]*c1) * inv);
                *(s16x4*)(dst + 8*i + 4*hi) = st;
            } else {
                const int t3 = i - 4;
                #pragma unroll
                for (int j = 0; j < 4; j++) st[j] = f2bf((o1[4*t3+j]*c0 + p[j]*c1) * inv);
                *(s16x4*)(dst + 32 + 8*t3 + 4*hi) = st;
            }
        }
    }
}

// ---------------------------------------------------------------------------
extern "C" void kernel_launch(void* const* d_in, const int* in_sizes, int n_in,
                              void* d_out, int out_size, void* d_ws, size_t ws_size,
                              hipStream_t stream)
{
    const float* x     = (const float*)d_in[0];
    const float* Wqkv  = (const float*)d_in[1];
    const float* qg    = (const float*)d_in[2];
    const float* qbeta = (const float*)d_in[3];
    const float* kg    = (const float*)d_in[4];
    const float* kbeta = (const float*)d_in[5];
    const float* Wproj = (const float*)d_in[6];
    const float* bproj = (const float*)d_in[7];
    float* out = (float*)d_out;

    char* ws = (char*)d_ws;
    const size_t MB = 1024*1024;
    short* xb     = (short*)(ws);              // 8 MB; dead after gemm<0>
    short* aout   = (short*)(ws);              // reuses xb slot (written by attn)
    short* wqkvb  = (short*)(ws + 8*MB);       // 6 MB
    short* wprojb = (short*)(ws + 14*MB);      // 2 MB (live until gemm<1>)
    short* q      = (short*)(ws + 16*MB);      // 8 MB
    short* KP     = (short*)(ws + 24*MB);      // 8 MB (fragment-order K)
    short* VP     = (short*)(ws + 32*MB);      // 8 MB (fragment-order V)

    // 1. fp32 -> bf16 conversions
    convert3<<<dim3(4096), 256, 0, stream>>>(x, Wqkv, Wproj, xb, wqkvb, wprojb);

    // 2. QKV GEMM + fused q/k LayerNorm + fused K/V fragment repack
    gemm_bf16<0><<<dim3(3*DIM/128, ROWS/128), 256, 0, stream>>>(
        xb, wqkvb, nullptr, qg, qbeta, kg, kbeta, q, KP, VP, nullptr);

    // 3. Flash attention (q32/wave, 2-way split-K, shuffle-free softmax)
    attn_kernel<<<dim3(BATCH*HEADS, SEQ/64), 256, 0, stream>>>(q, KP, VP, aout);

    // 4. Projection GEMM + bias -> fp32 d_out
    gemm_bf16<1><<<dim3(DIM/128, ROWS/128), 256, 0, stream>>>(
        aout, wprojb, bproj, nullptr, nullptr, nullptr, nullptr,
        nullptr, nullptr, nullptr, out);
}

// Round 17
// 133.584 us; speedup vs baseline: 1.1180x; 1.0287x over previous
//
#include <hip/hip_runtime.h>

#define DIM 1024
#define HEADS 16
#define HD 64
#define BATCH 2
#define SEQ 2048
#define ROWS (BATCH*SEQ)          // 4096
#define EPS 1e-6f

typedef float f32x4  __attribute__((ext_vector_type(4)));
typedef float f32x16 __attribute__((ext_vector_type(16)));
typedef short s16x4  __attribute__((ext_vector_type(4)));
typedef short s16x8  __attribute__((ext_vector_type(8)));

static __device__ __forceinline__ short f2bf(float f) {
    union { float f; unsigned u; } x; x.f = f;
    unsigned r = x.u + 0x7FFFu + ((x.u >> 16) & 1u);
    return (short)(r >> 16);
}
static __device__ __forceinline__ s16x8 pack8(float4 lo, float4 hi) {
    s16x8 r;
    r[0]=f2bf(lo.x); r[1]=f2bf(lo.y); r[2]=f2bf(lo.z); r[3]=f2bf(lo.w);
    r[4]=f2bf(hi.x); r[5]=f2bf(hi.y); r[6]=f2bf(hi.z); r[7]=f2bf(hi.w);
    return r;
}
static __device__ __forceinline__ unsigned cvtpk(float a, float b) {
    unsigned r;
    asm("v_cvt_pk_bf16_f32 %0, %1, %2" : "=v"(r) : "v"(a), "v"(b));
    return r;
}
static __device__ __forceinline__ void gld16(short* l, const short* g) {
    __builtin_amdgcn_global_load_lds(
        (const __attribute__((address_space(1))) void*)g,
        (__attribute__((address_space(3))) void*)l, 16, 0, 0);
}

#define MFMA32(A,B,C) __builtin_amdgcn_mfma_f32_32x32x16_bf16(A, B, C, 0, 0, 0)
#define MFMA16(A,B,C) __builtin_amdgcn_mfma_f32_16x16x32_bf16(A, B, C, 0, 0, 0)

struct PA { s16x8 a, b; };
// P (lane's 32 keys for its q-col) -> two bf16 A-fragments (T12; proven r2-r16)
static __device__ __forceinline__ PA packP(const f32x16& s) {
    PA r;
    unsigned A0 = cvtpk(s[0], s[1]),  A1 = cvtpk(s[2], s[3]);
    unsigned B0 = cvtpk(s[4], s[5]),  B1 = cvtpk(s[6], s[7]);
    asm volatile("v_permlane32_swap_b32 %0, %1" : "+v"(A0), "+v"(B0));
    asm volatile("v_permlane32_swap_b32 %0, %1" : "+v"(A1), "+v"(B1));
    union { s16x8 v; unsigned u[4]; } w;
    w.u[0]=A0; w.u[1]=A1; w.u[2]=B0; w.u[3]=B1;
    r.a = w.v;
    unsigned C0 = cvtpk(s[8], s[9]),   C1 = cvtpk(s[10], s[11]);
    unsigned D0 = cvtpk(s[12], s[13]), D1 = cvtpk(s[14], s[15]);
    asm volatile("v_permlane32_swap_b32 %0, %1" : "+v"(C0), "+v"(D0));
    asm volatile("v_permlane32_swap_b32 %0, %1" : "+v"(C1), "+v"(D1));
    union { s16x8 v; unsigned u[4]; } w2;
    w2.u[0]=C0; w2.u[1]=C1; w2.u[2]=D0; w2.u[3]=D1;
    r.b = w2.v;
    return r;
}
static __device__ __forceinline__ float tree_max(const f32x16& s) {
    float t[8];
    #pragma unroll
    for (int i = 0; i < 8; i++) t[i] = fmaxf(s[i], s[i+8]);
    #pragma unroll
    for (int i = 0; i < 4; i++) t[i] = fmaxf(t[i], t[i+4]);
    return fmaxf(fmaxf(t[0], t[2]), fmaxf(t[1], t[3]));
}
static __device__ __forceinline__ float tree_sum(const f32x16& s) {
    float t[8];
    #pragma unroll
    for (int i = 0; i < 8; i++) t[i] = s[i] + s[i+8];
    #pragma unroll
    for (int i = 0; i < 4; i++) t[i] += t[i+4];
    return (t[0] + t[2]) + (t[1] + t[3]);
}

// ---------------------------------------------------------------------------
// fp32 -> bf16 conversion for x, W_qkv, W_proj (one pass, vectorized)
// ---------------------------------------------------------------------------
__global__ __launch_bounds__(256) void convert3(
    const float* __restrict__ x, const float* __restrict__ wq,
    const float* __restrict__ wp,
    short* __restrict__ xb, short* __restrict__ wqb, short* __restrict__ wpb)
{
    const int idx = blockIdx.x * 256 + threadIdx.x;   // one 8-elem chunk
    const int C1 = 4194304/8, C2 = 3145728/8;
    const float* src; short* dst; int off;
    if (idx < C1)            { src = x;  dst = xb;  off = idx; }
    else if (idx < C1 + C2)  { src = wq; dst = wqb; off = idx - C1; }
    else                     { src = wp; dst = wpb; off = idx - C1 - C2; }
    float4 a = ((const float4*)src)[off*2];
    float4 b = ((const float4*)src)[off*2 + 1];
    ((s16x8*)dst)[off] = pack8(a, b);
}

// ---------------------------------------------------------------------------
// bf16 GEMM (QKV only), m97 structure: 128x128 tile, BK=64, global_load_lds
// staging, XCD-aware bijective block swizzle. Fused per-head LayerNorm on
// q/k; q row-major; K/V written directly in MFMA-fragment order (KP/VP).
// ---------------------------------------------------------------------------
#define BKG 64

__global__ __launch_bounds__(256) void gemm_qkv(
    const short* __restrict__ A, const short* __restrict__ W,
    const float* __restrict__ qg, const float* __restrict__ qbeta,
    const float* __restrict__ kg, const float* __restrict__ kbeta,
    short* __restrict__ qb, short* __restrict__ kpb, short* __restrict__ vpb)
{
    alignas(16) __shared__ short As[128*BKG];
    alignas(16) __shared__ short Bs[128*BKG];
    const int tid  = threadIdx.x;
    const int lane = tid & 63, wave = tid >> 6;
    const int wr = wave >> 1, wc = wave & 1;
    const int c = lane & 15, g = lane >> 4;

    // XCD-aware bijective swizzle (nwg = 768, %8==0)
    const int nwg = gridDim.x * gridDim.y;
    const int cpx = nwg >> 3;
    const int flat = blockIdx.y * gridDim.x + blockIdx.x;
    const int swz = (flat & 7) * cpx + (flat >> 3);
    const int bx = swz % gridDim.x, by = swz / gridDim.x;
    const int brow = by * 128, bcol = bx * 128;

    const int srow = lane >> 3;
    const int scol = (lane & 7) * 8;
    const short* ag = A + (size_t)(brow + srow)*DIM + scol;
    const short* wg = W + (size_t)(bcol + srow)*DIM + scol;

    f32x4 acc[4][4] = {};

    for (int k0 = 0; k0 < DIM; k0 += BKG) {
        #pragma unroll
        for (int j = 0; j < 4; j++) {
            const int rg = (wave*4 + j) * 8;
            gld16(&As[rg*BKG], ag + (size_t)rg*DIM + k0);
            gld16(&Bs[rg*BKG], wg + (size_t)rg*DIM + k0);
        }
        __syncthreads();

        #pragma unroll
        for (int ks = 0; ks < 2; ks++) {
            s16x8 af[4], bf[4];
            #pragma unroll
            for (int m = 0; m < 4; m++)
                af[m] = *(const s16x8*)&As[(wr*64 + m*16 + c)*BKG + ks*32 + g*8];
            #pragma unroll
            for (int n = 0; n < 4; n++)
                bf[n] = *(const s16x8*)&Bs[(wc*64 + n*16 + c)*BKG + ks*32 + g*8];
            #pragma unroll
            for (int m = 0; m < 4; m++)
                #pragma unroll
                for (int n = 0; n < 4; n++)
                    acc[m][n] = MFMA16(af[m], bf[n], acc[m][n]);
        }
        __syncthreads();
    }

    const int colbase = bcol + wc*64;
    const int t = colbase >> 10;               // 0:q 1:k 2:v
    const int h = (colbase >> 6) & 15;
    float gam[4], bet[4];
    float scale = 1.0f;
    if (t < 2) {
        const float* G  = (t == 0) ? qg : kg;
        const float* Bt = (t == 0) ? qbeta : kbeta;
        #pragma unroll
        for (int n = 0; n < 4; n++) { gam[n] = G[n*16 + c]; bet[n] = Bt[n*16 + c]; }
        if (t == 0) scale = 0.125f * 1.44269504088896340736f;  // D^-0.5 * log2e
    }
    #pragma unroll
    for (int m = 0; m < 4; m++) {
        #pragma unroll
        for (int j = 0; j < 4; j++) {
            const int row = brow + wr*64 + m*16 + g*4 + j;
            const int bi = row >> 11, ni = row & (SEQ-1);
            const int bh = bi*HEADS + h;
            float v0 = acc[m][0][j], v1 = acc[m][1][j];
            float v2 = acc[m][2][j], v3 = acc[m][3][j];
            if (t < 2) {
                float s = (v0 + v1) + (v2 + v3);
                s += __shfl_xor(s, 1); s += __shfl_xor(s, 2);
                s += __shfl_xor(s, 4); s += __shfl_xor(s, 8);
                const float mu = s * 0.015625f;
                v0 -= mu; v1 -= mu; v2 -= mu; v3 -= mu;
                float vv = (v0*v0 + v1*v1) + (v2*v2 + v3*v3);
                vv += __shfl_xor(vv, 1); vv += __shfl_xor(vv, 2);
                vv += __shfl_xor(vv, 4); vv += __shfl_xor(vv, 8);
                const float rstd = rsqrtf(vv * 0.015625f + EPS);
                v0 = (v0*rstd*gam[0] + bet[0]) * scale;
                v1 = (v1*rstd*gam[1] + bet[1]) * scale;
                v2 = (v2*rstd*gam[2] + bet[2]) * scale;
                v3 = (v3*rstd*gam[3] + bet[3]) * scale;
            }
            if (t == 0) {
                const size_t rb = ((size_t)bh*SEQ + ni)*HD;
                qb[rb + 0*16 + c] = f2bf(v0);
                qb[rb + 1*16 + c] = f2bf(v1);
                qb[rb + 2*16 + c] = f2bf(v2);
                qb[rb + 3*16 + c] = f2bf(v3);
            } else {
                const size_t tb = ((size_t)bh*64 + (ni >> 5)) * 2048;
                const int kl = ni & 31;
                if (t == 1) {
                    const size_t b2 = tb + (size_t)(((c >> 3)*32 + kl)*8 + (c & 7));
                    kpb[b2 + 0*512] = f2bf(v0);
                    kpb[b2 + 1*512] = f2bf(v1);
                    kpb[b2 + 2*512] = f2bf(v2);
                    kpb[b2 + 3*512] = f2bf(v3);
                } else {
                    const int hi2 = (kl & 15) >> 3;
                    const size_t b0 = tb + (size_t)((2*(kl >> 4))*512 + (hi2*32)*8 + (kl & 7));
                    vpb[b0 + (size_t)(c)*8]        = f2bf(v0);
                    vpb[b0 + (size_t)(16 + c)*8]   = f2bf(v1);
                    vpb[b0 + 512 + (size_t)(c)*8]      = f2bf(v2);
                    vpb[b0 + 512 + (size_t)(16 + c)*8] = f2bf(v3);
                }
            }
        }
    }
}

// ---------------------------------------------------------------------------
// Projection GEMM: 64x64x64 tile, 4 waves in 2x2 (32x32 each), grid 16x64 =
// 1024 blocks -> 4 blocks/CU (vs 1 with the 128^2 tile) so four K-loops
// interleave per SIMD. Same gld16 staging pattern and K-accumulation order
// as the 128^2 kernel (bit-identical output). Bias add, fp32 out.
// ---------------------------------------------------------------------------
__global__ __launch_bounds__(256) void gemm_proj(
    const short* __restrict__ A, const short* __restrict__ W,
    const float* __restrict__ bias, float* __restrict__ out)
{
    alignas(16) __shared__ short As[64*64];
    alignas(16) __shared__ short Bs[64*64];
    const int tid  = threadIdx.x;
    const int lane = tid & 63, wave = tid >> 6;
    const int wr = wave >> 1, wc = wave & 1;
    const int c = lane & 15, g = lane >> 4;

    // XCD-aware bijective swizzle (nwg = 1024, %8==0)
    const int cpx = (gridDim.x * gridDim.y) >> 3;
    const int flat = blockIdx.y * gridDim.x + blockIdx.x;
    const int swz = (flat & 7) * cpx + (flat >> 3);
    const int bx = swz % gridDim.x, by = swz / gridDim.x;
    const int brow = by * 64, bcol = bx * 64;

    const int srow = lane >> 3;
    const int scol = (lane & 7) * 8;
    const short* ag = A + (size_t)(brow + srow)*DIM + scol;
    const short* wg = W + (size_t)(bcol + srow)*DIM + scol;

    f32x4 acc[2][2] = {};

    for (int k0 = 0; k0 < DIM; k0 += 64) {
        #pragma unroll
        for (int j = 0; j < 2; j++) {
            const int rg = (wave*2 + j) * 8;
            gld16(&As[rg*64], ag + (size_t)rg*DIM + k0);
            gld16(&Bs[rg*64], wg + (size_t)rg*DIM + k0);
        }
        __syncthreads();

        #pragma unroll
        for (int ks = 0; ks < 2; ks++) {
            s16x8 af[2], bf[2];
            #pragma unroll
            for (int m = 0; m < 2; m++)
                af[m] = *(const s16x8*)&As[(wr*32 + m*16 + c)*64 + ks*32 + g*8];
            #pragma unroll
            for (int n = 0; n < 2; n++)
                bf[n] = *(const s16x8*)&Bs[(wc*32 + n*16 + c)*64 + ks*32 + g*8];
            #pragma unroll
            for (int m = 0; m < 2; m++)
                #pragma unroll
                for (int n = 0; n < 2; n++)
                    acc[m][n] = MFMA16(af[m], bf[n], acc[m][n]);
        }
        __syncthreads();
    }

    #pragma unroll
    for (int n = 0; n < 2; n++) {
        const int col = bcol + wc*32 + n*16 + c;
        const float bv = bias[col];
        #pragma unroll
        for (int m = 0; m < 2; m++) {
            #pragma unroll
            for (int j = 0; j < 4; j++) {
                const int row = brow + wr*32 + m*16 + g*4 + j;
                out[(size_t)row*DIM + col] = acc[m][n][j] + bv;
            }
        }
    }
}

// ---------------------------------------------------------------------------
// Flash attention: r16 exact (q32/wave, 2-way split-K, launch_bounds(256,4),
// single kc/vc banks, shuffle-free softmax fast path, exp2f, T12/T13,
// deferred cross-half sum, 2-way LDS merge).
// ---------------------------------------------------------------------------
__global__ __launch_bounds__(256, 4) void attn_kernel(
    const short* __restrict__ qbuf, const short* __restrict__ KP,
    const short* __restrict__ VP, short* __restrict__ aout)
{
    alignas(16) __shared__ float OL[2][64][32];   // [qsub][lane][reg]
    __shared__ float ML[2][2][64];                // [qsub][{m,l}][lane]

    const int bh = blockIdx.x, qt = blockIdx.y;
    const int tid = threadIdx.x, wave = tid >> 6, lane = tid & 63;
    const int qsub = wave >> 1, half = wave & 1;
    const int l31 = lane & 31, hi = lane >> 5;
    const int q0 = qt*64 + qsub*32;

    s16x8 qf[4];
    const short* qrow = qbuf + ((size_t)bh*SEQ + q0 + l31)*HD + 8*hi;
    #pragma unroll
    for (int ks = 0; ks < 4; ks++) qf[ks] = *(const s16x8*)(qrow + 16*ks);

    const short* kp = KP + ((size_t)bh*64 + half*32)*2048 + lane*8;
    const short* vp = VP + ((size_t)bh*64 + half*32)*2048 + lane*8;

    // prologue: tile 0 of this wave's K-half
    s16x8 kc0 = *(const s16x8*)(kp);
    s16x8 kc1 = *(const s16x8*)(kp + 512);
    s16x8 kc2 = *(const s16x8*)(kp + 1024);
    s16x8 kc3 = *(const s16x8*)(kp + 1536);
    s16x8 vc0 = *(const s16x8*)(vp);
    s16x8 vc1 = *(const s16x8*)(vp + 512);
    s16x8 vc2 = *(const s16x8*)(vp + 1024);
    s16x8 vc3 = *(const s16x8*)(vp + 1536);

    f32x16 o0 = {}, o1 = {};
    float m = -1e30f, l = 0.f;

    for (int it = 0; it < 32; it++) {
        // S^T = K*Q : lane holds 16 keys for q = q0+l31
        f32x16 s = {};
        __builtin_amdgcn_s_setprio(1);
        s = MFMA32(kc0, qf[0], s);
        s = MFMA32(kc1, qf[1], s);
        s = MFMA32(kc2, qf[2], s);
        s = MFMA32(kc3, qf[3], s);
        __builtin_amdgcn_s_setprio(0);

        // reload kc for next tile NOW (covered by softmax + PV below)
        const int nt = ((it + 1) & 31) * 2048;
        kc0 = *(const s16x8*)(kp + nt);
        kc1 = *(const s16x8*)(kp + nt + 512);
        kc2 = *(const s16x8*)(kp + nt + 1024);
        kc3 = *(const s16x8*)(kp + nt + 1536);
        __builtin_amdgcn_sched_barrier(0);

        // softmax: shuffle-free fast path (T13 vote on lane-local max)
        float pmax = tree_max(s);
        if (!__all(pmax - m <= 8.0f)) {           // rare, wave-uniform
            pmax = fmaxf(pmax, __shfl_xor(pmax, 32));   // true row max
            float mn = fmaxf(m, pmax);
            float corr = exp2f(m - mn);
            #pragma unroll
            for (int i = 0; i < 16; i++) { o0[i] *= corr; o1[i] *= corr; }
            l *= corr;
            m = mn;
        }
        #pragma unroll
        for (int i = 0; i < 16; i++) s[i] = exp2f(s[i] - m);
        l += tree_sum(s);                         // per half-lane partial

        // P -> bf16 A-fragments (T12)
        PA pa = packP(s);

        // O^T += V^T * P
        __builtin_amdgcn_s_setprio(1);
        o0 = MFMA32(vc0, pa.a, o0);
        o1 = MFMA32(vc1, pa.a, o1);
        o0 = MFMA32(vc2, pa.b, o0);
        o1 = MFMA32(vc3, pa.b, o1);
        __builtin_amdgcn_s_setprio(0);

        // reload vc for next tile (covered by next iter's S phase + softmax)
        vc0 = *(const s16x8*)(vp + nt);
        vc1 = *(const s16x8*)(vp + nt + 512);
        vc2 = *(const s16x8*)(vp + nt + 1024);
        vc3 = *(const s16x8*)(vp + nt + 1536);
    }

    // deferred cross-half sum (exact: m mirror-identical throughout)
    l += __shfl_xor(l, 32);

    // ---- merge the two K-halves (r16 exact) ----
    if (half == 1) {
        float* ob = &OL[qsub][lane][0];
        #pragma unroll
        for (int i = 0; i < 8; i++) {
            const int slot = (i + (lane & 7)) & 7;
            f32x4 v;
            if (i < 4) { v[0]=o0[4*i]; v[1]=o0[4*i+1]; v[2]=o0[4*i+2]; v[3]=o0[4*i+3]; }
            else { const int j = i-4; v[0]=o1[4*j]; v[1]=o1[4*j+1]; v[2]=o1[4*j+2]; v[3]=o1[4*j+3]; }
            *(f32x4*)(ob + slot*4) = v;
        }
        ML[qsub][0][lane] = m;
        ML[qsub][1][lane] = l;
    }
    __syncthreads();
    if (half == 0) {
        const float m1 = ML[qsub][0][lane];
        const float l1 = ML[qsub][1][lane];
        const float ms = fmaxf(m, m1);
        const float c0 = exp2f(m - ms), c1 = exp2f(m1 - ms);
        const float inv = 1.0f / (l*c0 + l1*c1);
        const float* ob = &OL[qsub][lane][0];
        const int b = bh >> 4, h = bh & 15;
        short* dst = aout + ((size_t)(b*SEQ + q0 + l31))*DIM + h*HD;
        #pragma unroll
        for (int i = 0; i < 8; i++) {
            const int slot = (i + (lane & 7)) & 7;
            f32x4 p = *(const f32x4*)(ob + slot*4);
            s16x4 st;
            if (i < 4) {
                #pragma unroll
                for (int j = 0; j < 4; j++) st[j] = f2bf((o0[4*i+j]*c0 + p[j]*c1) * inv);
                *(s16x4*)(dst + 8*i + 4*hi) = st;
            } else {
                const int t3 = i - 4;
                #pragma unroll
                for (int j = 0; j < 4; j++) st[j] = f2bf((o1[4*t3+j]*c0 + p[j]*c1) * inv);
                *(s16x4*)(dst + 32 + 8*t3 + 4*hi) = st;
            }
        }
    }
}

// ---------------------------------------------------------------------------
extern "C" void kernel_launch(void* const* d_in, const int* in_sizes, int n_in,
                              void* d_out, int out_size, void* d_ws, size_t ws_size,
                              hipStream_t stream)
{
    const float* x     = (const float*)d_in[0];
    const float* Wqkv  = (const float*)d_in[1];
    const float* qg    = (const float*)d_in[2];
    const float* qbeta = (const float*)d_in[3];
    const float* kg    = (const float*)d_in[4];
    const float* kbeta = (const float*)d_in[5];
    const float* Wproj = (const float*)d_in[6];
    const float* bproj = (const float*)d_in[7];
    float* out = (float*)d_out;

    char* ws = (char*)d_ws;
    const size_t MB = 1024*1024;
    short* xb     = (short*)(ws);              // 8 MB; dead after gemm_qkv
    short* aout   = (short*)(ws);              // reuses xb slot (written by attn)
    short* wqkvb  = (short*)(ws + 8*MB);       // 6 MB
    short* wprojb = (short*)(ws + 14*MB);      // 2 MB (live until gemm_proj)
    short* q      = (short*)(ws + 16*MB);      // 8 MB
    short* KP     = (short*)(ws + 24*MB);      // 8 MB (fragment-order K)
    short* VP     = (short*)(ws + 32*MB);      // 8 MB (fragment-order V)

    // 1. fp32 -> bf16 conversions
    convert3<<<dim3(4096), 256, 0, stream>>>(x, Wqkv, Wproj, xb, wqkvb, wprojb);

    // 2. QKV GEMM + fused q/k LayerNorm + fused K/V fragment repack
    gemm_qkv<<<dim3(3*DIM/128, ROWS/128), 256, 0, stream>>>(
        xb, wqkvb, qg, qbeta, kg, kbeta, q, KP, VP);

    // 3. Flash attention (q32/wave, 2-way split-K, shuffle-free softmax)
    attn_kernel<<<dim3(BATCH*HEADS, SEQ/64), 256, 0, stream>>>(q, KP, VP, aout);

    // 4. Projection GEMM (64x64 tile, 4 blocks/CU) + bias -> fp32 d_out
    gemm_proj<<<dim3(DIM/64, ROWS/64), 256, 0, stream>>>(
        aout, wprojb, bproj, out);
}

// Round 18
// 132.343 us; speedup vs baseline: 1.1285x; 1.0094x over previous
//
#include <hip/hip_runtime.h>

#define DIM 1024
#define HEADS 16
#define HD 64
#define BATCH 2
#define SEQ 2048
#define ROWS (BATCH*SEQ)          // 4096
#define EPS 1e-6f

typedef float f32x4  __attribute__((ext_vector_type(4)));
typedef float f32x16 __attribute__((ext_vector_type(16)));
typedef short s16x4  __attribute__((ext_vector_type(4)));
typedef short s16x8  __attribute__((ext_vector_type(8)));

static __device__ __forceinline__ short f2bf(float f) {
    union { float f; unsigned u; } x; x.f = f;
    unsigned r = x.u + 0x7FFFu + ((x.u >> 16) & 1u);
    return (short)(r >> 16);
}
static __device__ __forceinline__ s16x8 pack8(float4 lo, float4 hi) {
    s16x8 r;
    r[0]=f2bf(lo.x); r[1]=f2bf(lo.y); r[2]=f2bf(lo.z); r[3]=f2bf(lo.w);
    r[4]=f2bf(hi.x); r[5]=f2bf(hi.y); r[6]=f2bf(hi.z); r[7]=f2bf(hi.w);
    return r;
}
static __device__ __forceinline__ unsigned cvtpk(float a, float b) {
    unsigned r;
    asm("v_cvt_pk_bf16_f32 %0, %1, %2" : "=v"(r) : "v"(a), "v"(b));
    return r;
}
static __device__ __forceinline__ void gld16(short* l, const short* g) {
    __builtin_amdgcn_global_load_lds(
        (const __attribute__((address_space(1))) void*)g,
        (__attribute__((address_space(3))) void*)l, 16, 0, 0);
}

#define MFMA32(A,B,C) __builtin_amdgcn_mfma_f32_32x32x16_bf16(A, B, C, 0, 0, 0)
#define MFMA16(A,B,C) __builtin_amdgcn_mfma_f32_16x16x32_bf16(A, B, C, 0, 0, 0)

struct PA { s16x8 a, b; };
// P (lane's 32 keys for its q-col) -> two bf16 A-fragments (T12; proven r2-r17)
static __device__ __forceinline__ PA packP(const f32x16& s) {
    PA r;
    unsigned A0 = cvtpk(s[0], s[1]),  A1 = cvtpk(s[2], s[3]);
    unsigned B0 = cvtpk(s[4], s[5]),  B1 = cvtpk(s[6], s[7]);
    asm volatile("v_permlane32_swap_b32 %0, %1" : "+v"(A0), "+v"(B0));
    asm volatile("v_permlane32_swap_b32 %0, %1" : "+v"(A1), "+v"(B1));
    union { s16x8 v; unsigned u[4]; } w;
    w.u[0]=A0; w.u[1]=A1; w.u[2]=B0; w.u[3]=B1;
    r.a = w.v;
    unsigned C0 = cvtpk(s[8], s[9]),   C1 = cvtpk(s[10], s[11]);
    unsigned D0 = cvtpk(s[12], s[13]), D1 = cvtpk(s[14], s[15]);
    asm volatile("v_permlane32_swap_b32 %0, %1" : "+v"(C0), "+v"(D0));
    asm volatile("v_permlane32_swap_b32 %0, %1" : "+v"(C1), "+v"(D1));
    union { s16x8 v; unsigned u[4]; } w2;
    w2.u[0]=C0; w2.u[1]=C1; w2.u[2]=D0; w2.u[3]=D1;
    r.b = w2.v;
    return r;
}
static __device__ __forceinline__ float tree_max(const f32x16& s) {
    float t[8];
    #pragma unroll
    for (int i = 0; i < 8; i++) t[i] = fmaxf(s[i], s[i+8]);
    #pragma unroll
    for (int i = 0; i < 4; i++) t[i] = fmaxf(t[i], t[i+4]);
    return fmaxf(fmaxf(t[0], t[2]), fmaxf(t[1], t[3]));
}
static __device__ __forceinline__ float tree_sum(const f32x16& s) {
    float t[8];
    #pragma unroll
    for (int i = 0; i < 8; i++) t[i] = s[i] + s[i+8];
    #pragma unroll
    for (int i = 0; i < 4; i++) t[i] += t[i+4];
    return (t[0] + t[2]) + (t[1] + t[3]);
}

// ---------------------------------------------------------------------------
// fp32 -> bf16 conversion for x, W_qkv, W_proj (one pass, vectorized)
// ---------------------------------------------------------------------------
__global__ __launch_bounds__(256) void convert3(
    const float* __restrict__ x, const float* __restrict__ wq,
    const float* __restrict__ wp,
    short* __restrict__ xb, short* __restrict__ wqb, short* __restrict__ wpb)
{
    const int idx = blockIdx.x * 256 + threadIdx.x;   // one 8-elem chunk
    const int C1 = 4194304/8, C2 = 3145728/8;
    const float* src; short* dst; int off;
    if (idx < C1)            { src = x;  dst = xb;  off = idx; }
    else if (idx < C1 + C2)  { src = wq; dst = wqb; off = idx - C1; }
    else                     { src = wp; dst = wpb; off = idx - C1 - C2; }
    float4 a = ((const float4*)src)[off*2];
    float4 b = ((const float4*)src)[off*2 + 1];
    ((s16x8*)dst)[off] = pack8(a, b);
}

// ---------------------------------------------------------------------------
// bf16 GEMM (QKV only), m97 structure: 128x128 tile, BK=64, global_load_lds
// staging, XCD-aware bijective block swizzle. Fused per-head LayerNorm on
// q/k; q row-major; K/V written directly in MFMA-fragment order (KP/VP).
// ---------------------------------------------------------------------------
#define BKG 64

__global__ __launch_bounds__(256) void gemm_qkv(
    const short* __restrict__ A, const short* __restrict__ W,
    const float* __restrict__ qg, const float* __restrict__ qbeta,
    const float* __restrict__ kg, const float* __restrict__ kbeta,
    short* __restrict__ qb, short* __restrict__ kpb, short* __restrict__ vpb)
{
    alignas(16) __shared__ short As[128*BKG];
    alignas(16) __shared__ short Bs[128*BKG];
    const int tid  = threadIdx.x;
    const int lane = tid & 63, wave = tid >> 6;
    const int wr = wave >> 1, wc = wave & 1;
    const int c = lane & 15, g = lane >> 4;

    // XCD-aware bijective swizzle (nwg = 768, %8==0)
    const int nwg = gridDim.x * gridDim.y;
    const int cpx = nwg >> 3;
    const int flat = blockIdx.y * gridDim.x + blockIdx.x;
    const int swz = (flat & 7) * cpx + (flat >> 3);
    const int bx = swz % gridDim.x, by = swz / gridDim.x;
    const int brow = by * 128, bcol = bx * 128;

    const int srow = lane >> 3;
    const int scol = (lane & 7) * 8;
    const short* ag = A + (size_t)(brow + srow)*DIM + scol;
    const short* wg = W + (size_t)(bcol + srow)*DIM + scol;

    f32x4 acc[4][4] = {};

    for (int k0 = 0; k0 < DIM; k0 += BKG) {
        #pragma unroll
        for (int j = 0; j < 4; j++) {
            const int rg = (wave*4 + j) * 8;
            gld16(&As[rg*BKG], ag + (size_t)rg*DIM + k0);
            gld16(&Bs[rg*BKG], wg + (size_t)rg*DIM + k0);
        }
        __syncthreads();

        #pragma unroll
        for (int ks = 0; ks < 2; ks++) {
            s16x8 af[4], bf[4];
            #pragma unroll
            for (int m = 0; m < 4; m++)
                af[m] = *(const s16x8*)&As[(wr*64 + m*16 + c)*BKG + ks*32 + g*8];
            #pragma unroll
            for (int n = 0; n < 4; n++)
                bf[n] = *(const s16x8*)&Bs[(wc*64 + n*16 + c)*BKG + ks*32 + g*8];
            #pragma unroll
            for (int m = 0; m < 4; m++)
                #pragma unroll
                for (int n = 0; n < 4; n++)
                    acc[m][n] = MFMA16(af[m], bf[n], acc[m][n]);
        }
        __syncthreads();
    }

    const int colbase = bcol + wc*64;
    const int t = colbase >> 10;               // 0:q 1:k 2:v
    const int h = (colbase >> 6) & 15;
    float gam[4], bet[4];
    float scale = 1.0f;
    if (t < 2) {
        const float* G  = (t == 0) ? qg : kg;
        const float* Bt = (t == 0) ? qbeta : kbeta;
        #pragma unroll
        for (int n = 0; n < 4; n++) { gam[n] = G[n*16 + c]; bet[n] = Bt[n*16 + c]; }
        if (t == 0) scale = 0.125f * 1.44269504088896340736f;  // D^-0.5 * log2e
    }
    #pragma unroll
    for (int m = 0; m < 4; m++) {
        #pragma unroll
        for (int j = 0; j < 4; j++) {
            const int row = brow + wr*64 + m*16 + g*4 + j;
            const int bi = row >> 11, ni = row & (SEQ-1);
            const int bh = bi*HEADS + h;
            float v0 = acc[m][0][j], v1 = acc[m][1][j];
            float v2 = acc[m][2][j], v3 = acc[m][3][j];
            if (t < 2) {
                float s = (v0 + v1) + (v2 + v3);
                s += __shfl_xor(s, 1); s += __shfl_xor(s, 2);
                s += __shfl_xor(s, 4); s += __shfl_xor(s, 8);
                const float mu = s * 0.015625f;
                v0 -= mu; v1 -= mu; v2 -= mu; v3 -= mu;
                float vv = (v0*v0 + v1*v1) + (v2*v2 + v3*v3);
                vv += __shfl_xor(vv, 1); vv += __shfl_xor(vv, 2);
                vv += __shfl_xor(vv, 4); vv += __shfl_xor(vv, 8);
                const float rstd = rsqrtf(vv * 0.015625f + EPS);
                v0 = (v0*rstd*gam[0] + bet[0]) * scale;
                v1 = (v1*rstd*gam[1] + bet[1]) * scale;
                v2 = (v2*rstd*gam[2] + bet[2]) * scale;
                v3 = (v3*rstd*gam[3] + bet[3]) * scale;
            }
            if (t == 0) {
                const size_t rb = ((size_t)bh*SEQ + ni)*HD;
                qb[rb + 0*16 + c] = f2bf(v0);
                qb[rb + 1*16 + c] = f2bf(v1);
                qb[rb + 2*16 + c] = f2bf(v2);
                qb[rb + 3*16 + c] = f2bf(v3);
            } else {
                const size_t tb = ((size_t)bh*64 + (ni >> 5)) * 2048;
                const int kl = ni & 31;
                if (t == 1) {
                    const size_t b2 = tb + (size_t)(((c >> 3)*32 + kl)*8 + (c & 7));
                    kpb[b2 + 0*512] = f2bf(v0);
                    kpb[b2 + 1*512] = f2bf(v1);
                    kpb[b2 + 2*512] = f2bf(v2);
                    kpb[b2 + 3*512] = f2bf(v3);
                } else {
                    const int hi2 = (kl & 15) >> 3;
                    const size_t b0 = tb + (size_t)((2*(kl >> 4))*512 + (hi2*32)*8 + (kl & 7));
                    vpb[b0 + (size_t)(c)*8]        = f2bf(v0);
                    vpb[b0 + (size_t)(16 + c)*8]   = f2bf(v1);
                    vpb[b0 + 512 + (size_t)(c)*8]      = f2bf(v2);
                    vpb[b0 + 512 + (size_t)(16 + c)*8] = f2bf(v3);
                }
            }
        }
    }
}

// ---------------------------------------------------------------------------
// Projection GEMM: 64x64x64 tile, 4 waves in 2x2 (32x32 each), grid 16x64 =
// 1024 blocks -> 4 blocks/CU. Same gld16 staging pattern and K-accumulation
// order as the 128^2 kernel (bit-identical output). Bias add, fp32 out.
// ---------------------------------------------------------------------------
__global__ __launch_bounds__(256) void gemm_proj(
    const short* __restrict__ A, const short* __restrict__ W,
    const float* __restrict__ bias, float* __restrict__ out)
{
    alignas(16) __shared__ short As[64*64];
    alignas(16) __shared__ short Bs[64*64];
    const int tid  = threadIdx.x;
    const int lane = tid & 63, wave = tid >> 6;
    const int wr = wave >> 1, wc = wave & 1;
    const int c = lane & 15, g = lane >> 4;

    // XCD-aware bijective swizzle (nwg = 1024, %8==0)
    const int cpx = (gridDim.x * gridDim.y) >> 3;
    const int flat = blockIdx.y * gridDim.x + blockIdx.x;
    const int swz = (flat & 7) * cpx + (flat >> 3);
    const int bx = swz % gridDim.x, by = swz / gridDim.x;
    const int brow = by * 64, bcol = bx * 64;

    const int srow = lane >> 3;
    const int scol = (lane & 7) * 8;
    const short* ag = A + (size_t)(brow + srow)*DIM + scol;
    const short* wg = W + (size_t)(bcol + srow)*DIM + scol;

    f32x4 acc[2][2] = {};

    for (int k0 = 0; k0 < DIM; k0 += 64) {
        #pragma unroll
        for (int j = 0; j < 2; j++) {
            const int rg = (wave*2 + j) * 8;
            gld16(&As[rg*64], ag + (size_t)rg*DIM + k0);
            gld16(&Bs[rg*64], wg + (size_t)rg*DIM + k0);
        }
        __syncthreads();

        #pragma unroll
        for (int ks = 0; ks < 2; ks++) {
            s16x8 af[2], bf[2];
            #pragma unroll
            for (int m = 0; m < 2; m++)
                af[m] = *(const s16x8*)&As[(wr*32 + m*16 + c)*64 + ks*32 + g*8];
            #pragma unroll
            for (int n = 0; n < 2; n++)
                bf[n] = *(const s16x8*)&Bs[(wc*32 + n*16 + c)*64 + ks*32 + g*8];
            #pragma unroll
            for (int m = 0; m < 2; m++)
                #pragma unroll
                for (int n = 0; n < 2; n++)
                    acc[m][n] = MFMA16(af[m], bf[n], acc[m][n]);
        }
        __syncthreads();
    }

    #pragma unroll
    for (int n = 0; n < 2; n++) {
        const int col = bcol + wc*32 + n*16 + c;
        const float bv = bias[col];
        #pragma unroll
        for (int m = 0; m < 2; m++) {
            #pragma unroll
            for (int j = 0; j < 4; j++) {
                const int row = brow + wr*32 + m*16 + g*4 + j;
                out[(size_t)row*DIM + col] = acc[m][n][j] + bv;
            }
        }
    }
}

// ---------------------------------------------------------------------------
// Flash attention: r17 exact structure MINUS s_setprio (A/B: T5 is
// structure-conditional — hurts symmetric-wave kernels per m190; our 4
// waves/SIMD are symmetric, so priority boosting may serialize the
// inter-wave MFMA/VALU overlap we rely on). No numeric change.
// ---------------------------------------------------------------------------
__global__ __launch_bounds__(256, 4) void attn_kernel(
    const short* __restrict__ qbuf, const short* __restrict__ KP,
    const short* __restrict__ VP, short* __restrict__ aout)
{
    alignas(16) __shared__ float OL[2][64][32];   // [qsub][lane][reg]
    __shared__ float ML[2][2][64];                // [qsub][{m,l}][lane]

    const int bh = blockIdx.x, qt = blockIdx.y;
    const int tid = threadIdx.x, wave = tid >> 6, lane = tid & 63;
    const int qsub = wave >> 1, half = wave & 1;
    const int l31 = lane & 31, hi = lane >> 5;
    const int q0 = qt*64 + qsub*32;

    s16x8 qf[4];
    const short* qrow = qbuf + ((size_t)bh*SEQ + q0 + l31)*HD + 8*hi;
    #pragma unroll
    for (int ks = 0; ks < 4; ks++) qf[ks] = *(const s16x8*)(qrow + 16*ks);

    const short* kp = KP + ((size_t)bh*64 + half*32)*2048 + lane*8;
    const short* vp = VP + ((size_t)bh*64 + half*32)*2048 + lane*8;

    // prologue: tile 0 of this wave's K-half
    s16x8 kc0 = *(const s16x8*)(kp);
    s16x8 kc1 = *(const s16x8*)(kp + 512);
    s16x8 kc2 = *(const s16x8*)(kp + 1024);
    s16x8 kc3 = *(const s16x8*)(kp + 1536);
    s16x8 vc0 = *(const s16x8*)(vp);
    s16x8 vc1 = *(const s16x8*)(vp + 512);
    s16x8 vc2 = *(const s16x8*)(vp + 1024);
    s16x8 vc3 = *(const s16x8*)(vp + 1536);

    f32x16 o0 = {}, o1 = {};
    float m = -1e30f, l = 0.f;

    for (int it = 0; it < 32; it++) {
        // S^T = K*Q : lane holds 16 keys for q = q0+l31
        f32x16 s = {};
        s = MFMA32(kc0, qf[0], s);
        s = MFMA32(kc1, qf[1], s);
        s = MFMA32(kc2, qf[2], s);
        s = MFMA32(kc3, qf[3], s);

        // reload kc for next tile NOW (covered by softmax + PV below)
        const int nt = ((it + 1) & 31) * 2048;
        kc0 = *(const s16x8*)(kp + nt);
        kc1 = *(const s16x8*)(kp + nt + 512);
        kc2 = *(const s16x8*)(kp + nt + 1024);
        kc3 = *(const s16x8*)(kp + nt + 1536);
        __builtin_amdgcn_sched_barrier(0);

        // softmax: shuffle-free fast path (T13 vote on lane-local max)
        float pmax = tree_max(s);
        if (!__all(pmax - m <= 8.0f)) {           // rare, wave-uniform
            pmax = fmaxf(pmax, __shfl_xor(pmax, 32));   // true row max
            float mn = fmaxf(m, pmax);
            float corr = exp2f(m - mn);
            #pragma unroll
            for (int i = 0; i < 16; i++) { o0[i] *= corr; o1[i] *= corr; }
            l *= corr;
            m = mn;
        }
        #pragma unroll
        for (int i = 0; i < 16; i++) s[i] = exp2f(s[i] - m);
        l += tree_sum(s);                         // per half-lane partial

        // P -> bf16 A-fragments (T12)
        PA pa = packP(s);

        // O^T += V^T * P
        o0 = MFMA32(vc0, pa.a, o0);
        o1 = MFMA32(vc1, pa.a, o1);
        o0 = MFMA32(vc2, pa.b, o0);
        o1 = MFMA32(vc3, pa.b, o1);

        // reload vc for next tile (covered by next iter's S phase + softmax)
        vc0 = *(const s16x8*)(vp + nt);
        vc1 = *(const s16x8*)(vp + nt + 512);
        vc2 = *(const s16x8*)(vp + nt + 1024);
        vc3 = *(const s16x8*)(vp + nt + 1536);
    }

    // deferred cross-half sum (exact: m mirror-identical throughout)
    l += __shfl_xor(l, 32);

    // ---- merge the two K-halves (r17 exact) ----
    if (half == 1) {
        float* ob = &OL[qsub][lane][0];
        #pragma unroll
        for (int i = 0; i < 8; i++) {
            const int slot = (i + (lane & 7)) & 7;
            f32x4 v;
            if (i < 4) { v[0]=o0[4*i]; v[1]=o0[4*i+1]; v[2]=o0[4*i+2]; v[3]=o0[4*i+3]; }
            else { const int j = i-4; v[0]=o1[4*j]; v[1]=o1[4*j+1]; v[2]=o1[4*j+2]; v[3]=o1[4*j+3]; }
            *(f32x4*)(ob + slot*4) = v;
        }
        ML[qsub][0][lane] = m;
        ML[qsub][1][lane] = l;
    }
    __syncthreads();
    if (half == 0) {
        const float m1 = ML[qsub][0][lane];
        const float l1 = ML[qsub][1][lane];
        const float ms = fmaxf(m, m1);
        const float c0 = exp2f(m - ms), c1 = exp2f(m1 - ms);
        const float inv = 1.0f / (l*c0 + l1*c1);
        const float* ob = &OL[qsub][lane][0];
        const int b = bh >> 4, h = bh & 15;
        short* dst = aout + ((size_t)(b*SEQ + q0 + l31))*DIM + h*HD;
        #pragma unroll
        for (int i = 0; i < 8; i++) {
            const int slot = (i + (lane & 7)) & 7;
            f32x4 p = *(const f32x4*)(ob + slot*4);
            s16x4 st;
            if (i < 4) {
                #pragma unroll
                for (int j = 0; j < 4; j++) st[j] = f2bf((o0[4*i+j]*c0 + p[j]*c1) * inv);
                *(s16x4*)(dst + 8*i + 4*hi) = st;
            } else {
                const int t3 = i - 4;
                #pragma unroll
                for (int j = 0; j < 4; j++) st[j] = f2bf((o1[4*t3+j]*c0 + p[j]*c1) * inv);
                *(s16x4*)(dst + 32 + 8*t3 + 4*hi) = st;
            }
        }
    }
}

// ---------------------------------------------------------------------------
extern "C" void kernel_launch(void* const* d_in, const int* in_sizes, int n_in,
                              void* d_out, int out_size, void* d_ws, size_t ws_size,
                              hipStream_t stream)
{
    const float* x     = (const float*)d_in[0];
    const float* Wqkv  = (const float*)d_in[1];
    const float* qg    = (const float*)d_in[2];
    const float* qbeta = (const float*)d_in[3];
    const float* kg    = (const float*)d_in[4];
    const float* kbeta = (const float*)d_in[5];
    const float* Wproj = (const float*)d_in[6];
    const float* bproj = (const float*)d_in[7];
    float* out = (float*)d_out;

    char* ws = (char*)d_ws;
    const size_t MB = 1024*1024;
    short* xb     = (short*)(ws);              // 8 MB; dead after gemm_qkv
    short* aout   = (short*)(ws);              // reuses xb slot (written by attn)
    short* wqkvb  = (short*)(ws + 8*MB);       // 6 MB
    short* wprojb = (short*)(ws + 14*MB);      // 2 MB (live until gemm_proj)
    short* q      = (short*)(ws + 16*MB);      // 8 MB
    short* KP     = (short*)(ws + 24*MB);      // 8 MB (fragment-order K)
    short* VP     = (short*)(ws + 32*MB);      // 8 MB (fragment-order V)

    // 1. fp32 -> bf16 conversions
    convert3<<<dim3(4096), 256, 0, stream>>>(x, Wqkv, Wproj, xb, wqkvb, wprojb);

    // 2. QKV GEMM + fused q/k LayerNorm + fused K/V fragment repack
    gemm_qkv<<<dim3(3*DIM/128, ROWS/128), 256, 0, stream>>>(
        xb, wqkvb, qg, qbeta, kg, kbeta, q, KP, VP);

    // 3. Flash attention (q32/wave, 2-way split-K, no setprio)
    attn_kernel<<<dim3(BATCH*HEADS, SEQ/64), 256, 0, stream>>>(q, KP, VP, aout);

    // 4. Projection GEMM (64x64 tile, 4 blocks/CU) + bias -> fp32 d_out
    gemm_proj<<<dim3(DIM/64, ROWS/64), 256, 0, stream>>>(
        aout, wprojb, bproj, out);
}